// Round 5
// baseline (6454.436 us; speedup 1.0000x reference)
//
#include <hip/hip_runtime.h>
#include <math.h>

#define B 64
#define D 1024
#define H 16
#define DH 64
#define T 511
#define TT 512          // T+1
#define SMEM 256
#define DFF 4096
#define NLAYER 4
#define SCALE 0.125f
#define EPS 1e-5f
#define NBLK 512

__device__ __forceinline__ float dot4(const float4 a, const float4 b) {
    return a.x * b.x + a.y * b.y + a.z * b.z + a.w * b.w;
}
__device__ __forceinline__ float4 f4add(float4 a, float4 b) {
    return make_float4(a.x + b.x, a.y + b.y, a.z + b.z, a.w + b.w);
}

struct MP {
    const float *tgt, *cache, *K0, *V0, *K_mem, *V_mem;
    const float *sa_W, *sa_b, *sa_oW, *sa_ob, *ca_qW, *ca_qb, *ca_oW, *ca_ob;
    const float *W1, *b1, *W2, *b2, *ln1g, *ln1b, *ln2g, *ln2b, *ln3g, *ln3b;
    float *x, *ctx, *u, *Pq, *PA, *Pqkv, *Pc, *Pf1, *Pf2, *wp8, *sums8;
    unsigned *bar;
    float *out;
};

// ---------------------------------------------------------------------------
// Two-level grid barrier (16 groups x 32 blocks -> root), sense by parity.
// bar[0]=gen; bar[16+par*16]=root cnt; bar[64+par*256+g*16]=group cnt.
// ---------------------------------------------------------------------------
__device__ void gridbar(unsigned* bar, unsigned target) {
    __syncthreads();
    if (threadIdx.x == 0) {
        const unsigned par = target & 1u;
        unsigned* gen = bar;
        unsigned* cr  = bar + 16 + par * 16;
        unsigned* cg  = bar + 64 + par * 256 + (blockIdx.x & 15) * 16;
        __threadfence();
        if (atomicAdd(cg, 1u) == 31u) {
            if (atomicAdd(cr, 1u) == 15u) {
                #pragma unroll
                for (int i = 0; i < 16; ++i)
                    bar[64 + par * 256 + i * 16] = 0u;
                bar[16 + par * 16] = 0u;
                __threadfence();
                atomicAdd(gen, 1u);
            }
        }
        while (__hip_atomic_load(gen, __ATOMIC_ACQUIRE,
                                 __HIP_MEMORY_SCOPE_AGENT) < target)
            __builtin_amdgcn_s_sleep(2);
        __threadfence();
    }
    __syncthreads();
}

// ---------------------------------------------------------------------------
// GEMM tile: partial [64 b][128 o] for k in [kb, kb+nchunk*32). Thread 4b x 8o.
// ---------------------------------------------------------------------------
__device__ void dev_gemm(const float* __restrict__ A, int lda,
                         const float* __restrict__ W, int ldw,
                         float* __restrict__ Pout, int O,
                         int obase, int kb, int nchunk, float* sm)
{
    float* As = sm;             // [32][68]
    float* Ws = sm + 32 * 68;   // [32][132]
    const int tid = threadIdx.x;
    const int b0 = (tid >> 4) * 4;
    const int o0 = (tid & 15) * 8;
    float acc[4][8];
#pragma unroll
    for (int i = 0; i < 4; ++i)
#pragma unroll
        for (int j = 0; j < 8; ++j) acc[i][j] = 0.f;

    for (int c = 0; c < nchunk; ++c) {
        const int kc = kb + c * 32;
#pragma unroll
        for (int j = 0; j < 2; ++j) {
            const int f = tid + 256 * j;
            const int bb = f >> 3, k4 = f & 7;
            const float4 v = *(const float4*)(A + (size_t)bb * lda + kc + 4 * k4);
            As[(4 * k4 + 0) * 68 + bb] = v.x; As[(4 * k4 + 1) * 68 + bb] = v.y;
            As[(4 * k4 + 2) * 68 + bb] = v.z; As[(4 * k4 + 3) * 68 + bb] = v.w;
        }
#pragma unroll
        for (int j = 0; j < 4; ++j) {
            const int f = tid + 256 * j;
            const int oo = f >> 3, k4 = f & 7;
            const float4 v = *(const float4*)(W + (size_t)(obase + oo) * ldw + kc + 4 * k4);
            Ws[(4 * k4 + 0) * 132 + oo] = v.x; Ws[(4 * k4 + 1) * 132 + oo] = v.y;
            Ws[(4 * k4 + 2) * 132 + oo] = v.z; Ws[(4 * k4 + 3) * 132 + oo] = v.w;
        }
        __syncthreads();
#pragma unroll 8
        for (int k = 0; k < 32; ++k) {
            const float4 av = *(const float4*)(As + k * 68 + b0);
            const float4 w0 = *(const float4*)(Ws + k * 132 + o0);
            const float4 w1 = *(const float4*)(Ws + k * 132 + o0 + 4);
            const float a[4] = {av.x, av.y, av.z, av.w};
            const float w[8] = {w0.x, w0.y, w0.z, w0.w, w1.x, w1.y, w1.z, w1.w};
#pragma unroll
            for (int i = 0; i < 4; ++i)
#pragma unroll
                for (int j = 0; j < 8; ++j)
                    acc[i][j] = fmaf(a[i], w[j], acc[i][j]);
        }
        __syncthreads();
    }
#pragma unroll
    for (int i = 0; i < 4; ++i) {
        const float4 v0 = make_float4(acc[i][0], acc[i][1], acc[i][2], acc[i][3]);
        const float4 v1 = make_float4(acc[i][4], acc[i][5], acc[i][6], acc[i][7]);
        *(float4*)(Pout + (size_t)(b0 + i) * O + obase + o0) = v0;
        *(float4*)(Pout + (size_t)(b0 + i) * O + obase + o0 + 4) = v1;
    }
}

// ---------------------------------------------------------------------------
// GEMM with A = act(abias + sum of npart partials). Same tiling.
// ---------------------------------------------------------------------------
__device__ void dev_gemm_psum(const float* __restrict__ Pa, int npart,
                              const float* __restrict__ abias, bool relu, int Ka,
                              const float* __restrict__ W, int ldw,
                              float* __restrict__ Pout, int O,
                              int obase, int kb, int nchunk, float* sm)
{
    float* As = sm;
    float* Ws = sm + 32 * 68;
    const int tid = threadIdx.x;
    const int b0 = (tid >> 4) * 4;
    const int o0 = (tid & 15) * 8;
    float acc[4][8];
#pragma unroll
    for (int i = 0; i < 4; ++i)
#pragma unroll
        for (int j = 0; j < 8; ++j) acc[i][j] = 0.f;

    for (int c = 0; c < nchunk; ++c) {
        const int kc = kb + c * 32;
#pragma unroll
        for (int j = 0; j < 2; ++j) {
            const int f = tid + 256 * j;
            const int bb = f >> 3, k4 = f & 7;
            const int kg = kc + 4 * k4;
            float4 v = *(const float4*)(abias + kg);
            for (int s = 0; s < npart; ++s)
                v = f4add(v, *(const float4*)(Pa + (size_t)(s * 64 + bb) * Ka + kg));
            if (relu) {
                v.x = fmaxf(v.x, 0.f); v.y = fmaxf(v.y, 0.f);
                v.z = fmaxf(v.z, 0.f); v.w = fmaxf(v.w, 0.f);
            }
            As[(4 * k4 + 0) * 68 + bb] = v.x; As[(4 * k4 + 1) * 68 + bb] = v.y;
            As[(4 * k4 + 2) * 68 + bb] = v.z; As[(4 * k4 + 3) * 68 + bb] = v.w;
        }
#pragma unroll
        for (int j = 0; j < 4; ++j) {
            const int f = tid + 256 * j;
            const int oo = f >> 3, k4 = f & 7;
            const float4 v = *(const float4*)(W + (size_t)(obase + oo) * ldw + kc + 4 * k4);
            Ws[(4 * k4 + 0) * 132 + oo] = v.x; Ws[(4 * k4 + 1) * 132 + oo] = v.y;
            Ws[(4 * k4 + 2) * 132 + oo] = v.z; Ws[(4 * k4 + 3) * 132 + oo] = v.w;
        }
        __syncthreads();
#pragma unroll 8
        for (int k = 0; k < 32; ++k) {
            const float4 av = *(const float4*)(As + k * 68 + b0);
            const float4 w0 = *(const float4*)(Ws + k * 132 + o0);
            const float4 w1 = *(const float4*)(Ws + k * 132 + o0 + 4);
            const float a[4] = {av.x, av.y, av.z, av.w};
            const float w[8] = {w0.x, w0.y, w0.z, w0.w, w1.x, w1.y, w1.z, w1.w};
#pragma unroll
            for (int i = 0; i < 4; ++i)
#pragma unroll
                for (int j = 0; j < 8; ++j)
                    acc[i][j] = fmaf(a[i], w[j], acc[i][j]);
        }
        __syncthreads();
    }
#pragma unroll
    for (int i = 0; i < 4; ++i) {
        const float4 v0 = make_float4(acc[i][0], acc[i][1], acc[i][2], acc[i][3]);
        const float4 v1 = make_float4(acc[i][4], acc[i][5], acc[i][6], acc[i][7]);
        *(float4*)(Pout + (size_t)(b0 + i) * O + obase + o0) = v0;
        *(float4*)(Pout + (size_t)(b0 + i) * O + obase + o0 + 4) = v1;
    }
}

// ---------------------------------------------------------------------------
// u[b,h,dbase..+127] = sum_k q[b,h,k]*Wk[h*64+k][d]; q = sum 16 Pq + bq.
// ---------------------------------------------------------------------------
__device__ void dev_gemm_u(const float* __restrict__ Pq, const float* __restrict__ bq,
                           const float* __restrict__ Wk, int h, int dbase,
                           float* __restrict__ u, float* sm)
{
    float* As = sm;
    float* Ws = sm + 32 * 68;
    const int tid = threadIdx.x;
    const int b0 = (tid >> 4) * 4;
    const int o0 = (tid & 15) * 8;
    float acc[4][8];
#pragma unroll
    for (int i = 0; i < 4; ++i)
#pragma unroll
        for (int j = 0; j < 8; ++j) acc[i][j] = 0.f;

    for (int kc = 0; kc < DH; kc += 32) {
#pragma unroll
        for (int j = 0; j < 2; ++j) {
            const int f = tid + 256 * j;
            const int bb = f >> 3, k4 = f & 7;
            const int kg = h * DH + kc + 4 * k4;
            float4 v = *(const float4*)(bq + kg);
#pragma unroll
            for (int s = 0; s < 16; ++s)
                v = f4add(v, *(const float4*)(Pq + (size_t)(s * 64 + bb) * D + kg));
            As[(4 * k4 + 0) * 68 + bb] = v.x; As[(4 * k4 + 1) * 68 + bb] = v.y;
            As[(4 * k4 + 2) * 68 + bb] = v.z; As[(4 * k4 + 3) * 68 + bb] = v.w;
        }
#pragma unroll
        for (int j = 0; j < 4; ++j) {
            const int f = tid + 256 * j;
            const int k = f >> 5, d4 = f & 31;
            *(float4*)(Ws + k * 132 + 4 * d4) =
                *(const float4*)(Wk + (size_t)(h * DH + kc + k) * D + dbase + 4 * d4);
        }
        __syncthreads();
#pragma unroll 8
        for (int k = 0; k < 32; ++k) {
            const float4 av = *(const float4*)(As + k * 68 + b0);
            const float4 w0 = *(const float4*)(Ws + k * 132 + o0);
            const float4 w1 = *(const float4*)(Ws + k * 132 + o0 + 4);
            const float a[4] = {av.x, av.y, av.z, av.w};
            const float w[8] = {w0.x, w0.y, w0.z, w0.w, w1.x, w1.y, w1.z, w1.w};
#pragma unroll
            for (int i = 0; i < 4; ++i)
#pragma unroll
                for (int j = 0; j < 8; ++j)
                    acc[i][j] = fmaf(a[i], w[j], acc[i][j]);
        }
        __syncthreads();
    }
#pragma unroll
    for (int i = 0; i < 4; ++i) {
        const float4 v0 = make_float4(acc[i][0], acc[i][1], acc[i][2], acc[i][3]);
        const float4 v1 = make_float4(acc[i][4], acc[i][5], acc[i][6], acc[i][7]);
        float* ur = u + ((size_t)(b0 + i) * H + h) * D + dbase + o0;
        *(float4*)(ur) = v0;
        *(float4*)(ur + 4) = v1;
    }
}

// ---------------------------------------------------------------------------
// Streaming self-attn, 2 heads per 32-lane group. Block = (b, t8): 64 tokens.
// thread: hp=tid>>5 -> heads 2hp,2hp+1; seg=tid&31 -> d in [seg*32, seg*32+32).
// ---------------------------------------------------------------------------
__device__ void dev_sattn(const float* __restrict__ cache_i, const float* __restrict__ x,
                          const float* __restrict__ u, int b, int t8,
                          float* __restrict__ wp8, float* __restrict__ sums8, float* sm)
{
    const int tid = threadIdx.x;
    const int hp = tid >> 5;
    const int h0 = hp * 2, h1 = h0 + 1;
    const int seg = tid & 31;

    float4 u0[8], u1[8], a0[8], a1[8];
    const float* ub0 = u + ((size_t)(b * H + h0)) * D + seg * 32;
    const float* ub1 = u + ((size_t)(b * H + h1)) * D + seg * 32;
#pragma unroll
    for (int c = 0; c < 8; ++c) {
        float4 v = *(const float4*)(ub0 + 4 * c);
        u0[c] = make_float4(v.x * SCALE, v.y * SCALE, v.z * SCALE, v.w * SCALE);
        v = *(const float4*)(ub1 + 4 * c);
        u1[c] = make_float4(v.x * SCALE, v.y * SCALE, v.z * SCALE, v.w * SCALE);
        a0[c] = make_float4(0.f, 0.f, 0.f, 0.f);
        a1[c] = make_float4(0.f, 0.f, 0.f, 0.f);
    }
    float s0 = 0.f, s1 = 0.f;

    float* rowb = sm;   // [2][2][1024]
    const int tg0 = t8 * 64;
    const int lr = tid >> 7;            // staged row 0/1
    const int lcf = (tid & 127) * 8;    // 8 floats per thread

    const float* r0p = (tg0 + lr < T) ? cache_i + ((size_t)(tg0 + lr) * B + b) * D
                                      : x + (size_t)b * D;
    float4 pa = *(const float4*)(r0p + lcf);
    float4 pb = *(const float4*)(r0p + lcf + 4);

    for (int st = 0; st < 32; ++st) {
        const int p = st & 1;
        *(float4*)(rowb + p * 2048 + lr * 1024 + lcf) = pa;
        *(float4*)(rowb + p * 2048 + lr * 1024 + lcf + 4) = pb;
        __syncthreads();
        if (st + 1 < 32) {
            const int t = tg0 + 2 * (st + 1) + lr;
            const float* rp = (t < T) ? cache_i + ((size_t)t * B + b) * D
                                      : x + (size_t)b * D;
            pa = *(const float4*)(rp + lcf);
            pb = *(const float4*)(rp + lcf + 4);
        }
#pragma unroll
        for (int r = 0; r < 2; ++r) {
            const float* rowp = rowb + p * 2048 + r * 1024 + seg * 32;
            float4 rv[8];
            float d0 = 0.f, d1 = 0.f;
#pragma unroll
            for (int c = 0; c < 8; ++c) {
                rv[c] = *(const float4*)(rowp + 4 * c);
                d0 += dot4(u0[c], rv[c]);
                d1 += dot4(u1[c], rv[c]);
            }
#pragma unroll
            for (int m = 16; m >= 1; m >>= 1) {
                d0 += __shfl_xor(d0, m, 64);
                d1 += __shfl_xor(d1, m, 64);
            }
            const float e0 = __expf(d0), e1 = __expf(d1);
            s0 += e0; s1 += e1;
#pragma unroll
            for (int c = 0; c < 8; ++c) {
                a0[c].x = fmaf(e0, rv[c].x, a0[c].x);
                a0[c].y = fmaf(e0, rv[c].y, a0[c].y);
                a0[c].z = fmaf(e0, rv[c].z, a0[c].z);
                a0[c].w = fmaf(e0, rv[c].w, a0[c].w);
                a1[c].x = fmaf(e1, rv[c].x, a1[c].x);
                a1[c].y = fmaf(e1, rv[c].y, a1[c].y);
                a1[c].z = fmaf(e1, rv[c].z, a1[c].z);
                a1[c].w = fmaf(e1, rv[c].w, a1[c].w);
            }
        }
    }

    float* w0 = wp8 + ((size_t)((b * 8 + t8) * H + h0)) * D + seg * 32;
    float* w1 = wp8 + ((size_t)((b * 8 + t8) * H + h1)) * D + seg * 32;
#pragma unroll
    for (int c = 0; c < 8; ++c) {
        *(float4*)(w0 + 4 * c) = a0[c];
        *(float4*)(w1 + 4 * c) = a1[c];
    }
    if (seg == 0) {
        sums8[(b * 8 + t8) * H + h0] = s0;
        sums8[(b * 8 + t8) * H + h1] = s1;
    }
}

// ---------------------------------------------------------------------------
// ctx partial (one k-slice of 128): A = (sum 8 wp8 partials) * (1/sumE).
// ---------------------------------------------------------------------------
__device__ void dev_gemm_ctx(const float* __restrict__ wp8, const float* __restrict__ sums8,
                             const float* __restrict__ Wv, int h, int kslice,
                             float* __restrict__ Pout, float* sm)
{
    float* As = sm;
    float* Ws = sm + 32 * 68;
    float* sinv = sm + 6400;
    const int tid = threadIdx.x;
    if (tid < 64) {
        float s = 0.f;
#pragma unroll
        for (int t = 0; t < 8; ++t) s += sums8[(tid * 8 + t) * H + h];
        sinv[tid] = 1.f / s;
    }
    __syncthreads();

    const int b0 = (tid >> 4) * 4;
    const int o0 = (tid & 15) * 4;
    float acc[4][4];
#pragma unroll
    for (int i = 0; i < 4; ++i)
#pragma unroll
        for (int j = 0; j < 4; ++j) acc[i][j] = 0.f;

    const int kb = kslice * 128;
    for (int kc = 0; kc < 128; kc += 32) {
#pragma unroll
        for (int j = 0; j < 2; ++j) {
            const int f = tid + 256 * j;
            const int bb = f >> 3, k4 = f & 7;
            const int kg = kb + kc + 4 * k4;
            float4 v = make_float4(0.f, 0.f, 0.f, 0.f);
#pragma unroll
            for (int t = 0; t < 8; ++t)
                v = f4add(v, *(const float4*)(wp8 + ((size_t)((bb * 8 + t) * H + h)) * D + kg));
            const float iv = sinv[bb];
            As[(4 * k4 + 0) * 68 + bb] = v.x * iv; As[(4 * k4 + 1) * 68 + bb] = v.y * iv;
            As[(4 * k4 + 2) * 68 + bb] = v.z * iv; As[(4 * k4 + 3) * 68 + bb] = v.w * iv;
        }
#pragma unroll
        for (int j = 0; j < 2; ++j) {
            const int f = tid + 256 * j;
            const int oo = f >> 3, k4 = f & 7;
            const float4 v = *(const float4*)(Wv + (size_t)(h * DH + oo) * D + kb + kc + 4 * k4);
            Ws[(4 * k4 + 0) * 68 + oo] = v.x; Ws[(4 * k4 + 1) * 68 + oo] = v.y;
            Ws[(4 * k4 + 2) * 68 + oo] = v.z; Ws[(4 * k4 + 3) * 68 + oo] = v.w;
        }
        __syncthreads();
#pragma unroll 8
        for (int k = 0; k < 32; ++k) {
            const float4 av = *(const float4*)(As + k * 68 + b0);
            const float4 wv = *(const float4*)(Ws + k * 68 + o0);
            const float a[4] = {av.x, av.y, av.z, av.w};
            const float w[4] = {wv.x, wv.y, wv.z, wv.w};
#pragma unroll
            for (int i = 0; i < 4; ++i)
#pragma unroll
                for (int j = 0; j < 4; ++j)
                    acc[i][j] = fmaf(a[i], w[j], acc[i][j]);
        }
        __syncthreads();
    }
#pragma unroll
    for (int i = 0; i < 4; ++i) {
        const float4 v = make_float4(acc[i][0], acc[i][1], acc[i][2], acc[i][3]);
        *(float4*)(Pout + (size_t)(b0 + i) * D + h * DH + o0) = v;
    }
}

// ---------------------------------------------------------------------------
// finish + residual + LayerNorm for row b.
// ---------------------------------------------------------------------------
__device__ void dev_ln(const float* __restrict__ Pp, int npart,
                       const float* __restrict__ bias, const float* __restrict__ resid,
                       const float* __restrict__ gg, const float* __restrict__ bbv,
                       float* __restrict__ out, int b, float* sm)
{
    float* red = sm;
    float* red2 = sm + 8;
    const int tid = threadIdx.x;
    float4 v = ((const float4*)bias)[tid];
    v = f4add(v, ((const float4*)(resid + (size_t)b * D))[tid]);
    for (int s = 0; s < npart; ++s)
        v = f4add(v, ((const float4*)Pp)[(size_t)(s * 64 + b) * 256 + tid]);

    float ssum = v.x + v.y + v.z + v.w;
#pragma unroll
    for (int m = 32; m >= 1; m >>= 1) ssum += __shfl_xor(ssum, m, 64);
    if ((tid & 63) == 0) red[tid >> 6] = ssum;
    __syncthreads();
    const float mean = (red[0] + red[1] + red[2] + red[3]) * (1.f / D);
    const float dx = v.x - mean, dy = v.y - mean, dz = v.z - mean, dw = v.w - mean;
    float q = dx * dx + dy * dy + dz * dz + dw * dw;
#pragma unroll
    for (int m = 32; m >= 1; m >>= 1) q += __shfl_xor(q, m, 64);
    if ((tid & 63) == 0) red2[tid >> 6] = q;
    __syncthreads();
    const float var = (red2[0] + red2[1] + red2[2] + red2[3]) * (1.f / D);
    const float rs = rsqrtf(var + EPS);
    const float4 gv = ((const float4*)gg)[tid];
    const float4 bv = ((const float4*)bbv)[tid];
    float4 o;
    o.x = dx * rs * gv.x + bv.x;
    o.y = dy * rs * gv.y + bv.y;
    o.z = dz * rs * gv.z + bv.z;
    o.w = dw * rs * gv.w + bv.w;
    ((float4*)(out + (size_t)b * D))[tid] = o;
}

// ---------------------------------------------------------------------------
// Fused attention for one (b,h). q (and HASX k/v extra row) from partials.
// ---------------------------------------------------------------------------
template <int NS, bool HASX>
__device__ void dev_attn(const float* __restrict__ qP, const float* __restrict__ qbias,
                         int npart, int qpitch, int b, int h,
                         const float* __restrict__ Kb, const float* __restrict__ Vb,
                         int nk, float* __restrict__ ctx, float* sm)
{
    float* qs = sm;
    float* kx = sm + 64;
    float* vx = sm + 128;
    float* r1 = sm + 192;
    float* r2 = sm + 200;
    float* sa = sm + 256;          // NS
    float* red = sm + 768;         // 1088 floats; also q-build partials
    const int tid = threadIdx.x;
    __syncthreads();   // protect sm reuse across consecutive calls

    {
        const int grp = tid >> 6, col = tid & 63;
        const int np4 = npart >> 2;
        const int colg = h * DH + col;
        float aq = 0.f, ak = 0.f, av = 0.f;
        for (int s = grp * np4; s < (grp + 1) * np4; ++s) {
            const float* base = qP + (size_t)(s * 64 + b) * qpitch + colg;
            aq += base[0];
            if (HASX) { ak += base[D]; av += base[2 * D]; }
        }
        red[grp * 64 + col] = aq;
        if (HASX) {
            red[256 + grp * 64 + col] = ak;
            red[512 + grp * 64 + col] = av;
        }
        __syncthreads();
        if (tid < 64) {
            qs[tid] = qbias[h * DH + tid] + red[tid] + red[64 + tid] +
                      red[128 + tid] + red[192 + tid];
            if (HASX) {
                kx[tid] = qbias[D + h * DH + tid] + red[256 + tid] + red[320 + tid] +
                          red[384 + tid] + red[448 + tid];
                vx[tid] = qbias[2 * D + h * DH + tid] + red[512 + tid] + red[576 + tid] +
                          red[640 + tid] + red[704 + tid];
            }
        }
        __syncthreads();
    }

    const int ss = tid >> 2, pp = tid & 3;
    const float* Kbh = Kb + ((size_t)(b * H + h)) * nk * DH;
#pragma unroll 2
    for (int pass = 0; pass < NS / 64; ++pass) {
        const int s = pass * 64 + ss;
        const float* row = (!HASX || s < nk) ? (Kbh + (size_t)s * DH) : kx;
        const float4* rp = (const float4*)row;
        const float4* qp = (const float4*)qs;
        float acc = 0.f;
#pragma unroll
        for (int c = 0; c < 4; ++c) acc += dot4(rp[pp * 4 + c], qp[pp * 4 + c]);
        acc += __shfl_xor(acc, 1, 64);
        acc += __shfl_xor(acc, 2, 64);
        if (pp == 0) sa[s] = acc * SCALE;
    }
    __syncthreads();

    float m = -1e30f;
    for (int k = tid; k < NS; k += 256) m = fmaxf(m, sa[k]);
#pragma unroll
    for (int mm = 32; mm >= 1; mm >>= 1) m = fmaxf(m, __shfl_xor(m, mm, 64));
    if ((tid & 63) == 0) r1[tid >> 6] = m;
    __syncthreads();
    m = fmaxf(fmaxf(r1[0], r1[1]), fmaxf(r1[2], r1[3]));
    float sum = 0.f;
    for (int k = tid; k < NS; k += 256) {
        const float e = __expf(sa[k] - m);
        sa[k] = e;
        sum += e;
    }
#pragma unroll
    for (int mm = 32; mm >= 1; mm >>= 1) sum += __shfl_xor(sum, mm, 64);
    if ((tid & 63) == 0) r2[tid >> 6] = sum;
    __syncthreads();
    const float inv = 1.f / (r2[0] + r2[1] + r2[2] + r2[3]);

    const int dh4 = tid & 15, sq = tid >> 4;
    const float* Vbh = Vb + ((size_t)(b * H + h)) * nk * DH;
    float4 acc = make_float4(0.f, 0.f, 0.f, 0.f);
#pragma unroll 2
    for (int s = sq; s < NS; s += 16) {
        const float* row = (!HASX || s < nk) ? (Vbh + (size_t)s * DH) : vx;
        const float4 vv = *(const float4*)(row + dh4 * 4);
        const float aw = sa[s];
        acc.x += aw * vv.x; acc.y += aw * vv.y;
        acc.z += aw * vv.z; acc.w += aw * vv.w;
    }
    __syncthreads();
    *(float4*)(red + sq * 68 + dh4 * 4) = acc;
    __syncthreads();
    if (tid < 64) {
        float t = 0.f;
#pragma unroll
        for (int k = 0; k < 16; ++k) t += red[k * 68 + tid];
        ctx[(size_t)b * D + h * DH + tid] = t * inv;
    }
}

// ---------------------------------------------------------------------------
__global__ __launch_bounds__(256, 2) void mega(MP p)
{
    __shared__ float sm[6496];
    const int bid = blockIdx.x;
    unsigned bt = 0;
#define GB() do { ++bt; gridbar(p.bar, bt); } while (0)

    for (int L = 0; L < NLAYER; ++L) {
        const float* Wqkv = p.sa_W + (size_t)L * 3 * D * D;
        const float* bqkv = p.sa_b + (size_t)L * 3 * D;
        const float* xin = (L == 0) ? p.tgt : p.x;

        if (L == 0) {
            if (bid < 384) {
                const int og = bid % 24, ks = bid / 24;
                dev_gemm(p.tgt, D, Wqkv, D, p.Pqkv + (size_t)ks * B * 3 * D, 3 * D,
                         og * 128, ks * 64, 2, sm);
            }
            GB();
#pragma unroll 1
            for (int j = 0; j < 2; ++j) {
                const int pair = bid * 2 + j;
                dev_attn<TT, true>(p.Pqkv, bqkv, 16, 3 * D, pair >> 4, pair & 15,
                                   p.K0, p.V0, T, p.ctx, sm);
            }
            GB();
            if (bid < 256) {
                const int og = bid & 7, ks = bid >> 3;
                dev_gemm(p.ctx, D, p.sa_oW, D, p.PA + (size_t)ks * B * D, D,
                         og * 128, ks * 32, 1, sm);
            }
            GB();
        } else {
            const float* cache_i = p.cache + (size_t)L * T * B * D;
            if (bid < 128) {
                const int og = bid & 7, ks = bid >> 3;
                dev_gemm(p.x, D, Wqkv, D, p.Pq + (size_t)ks * B * D, D,
                         og * 128, ks * 64, 2, sm);
            }
            GB();
            if (bid < 128)
                dev_gemm_u(p.Pq, bqkv, Wqkv + (size_t)D * D, bid >> 3,
                           (bid & 7) * 128, p.u, sm);
            GB();
            dev_sattn(cache_i, p.x, p.u, bid >> 3, bid & 7, p.wp8, p.sums8, sm);
            GB();
            if (bid < 128)
                dev_gemm_ctx(p.wp8, p.sums8, Wqkv + (size_t)2 * D * D, bid >> 3,
                             bid & 7, p.Pc + (size_t)(bid & 7) * B * D, sm);
            GB();
            if (bid < 256) {
                const int og = bid & 7, ks = bid >> 3;
                dev_gemm_psum(p.Pc, 8, bqkv + 2 * D, false, D,
                              p.sa_oW + (size_t)L * D * D, D,
                              p.PA + (size_t)ks * B * D, D, og * 128, ks * 32, 1, sm);
            }
            GB();
        }

        if (bid < B)
            dev_ln(p.PA, 32, p.sa_ob + (size_t)L * D, xin,
                   p.ln1g + (size_t)L * D, p.ln1b + (size_t)L * D, p.x, bid, sm);
        GB();

        // cross attention
        if (bid < 256) {
            const int og = bid & 7, ks = bid >> 3;
            dev_gemm(p.x, D, p.ca_qW + (size_t)L * D * D, D,
                     p.PA + (size_t)ks * B * D, D, og * 128, ks * 32, 1, sm);
        }
        GB();
        {
            const float* Kc = p.K_mem + (size_t)L * B * H * SMEM * DH;
            const float* Vc = p.V_mem + (size_t)L * B * H * SMEM * DH;
#pragma unroll 1
            for (int j = 0; j < 2; ++j) {
                const int pair = bid * 2 + j;
                dev_attn<SMEM, false>(p.PA, p.ca_qb + (size_t)L * D, 32, D,
                                      pair >> 4, pair & 15, Kc, Vc, SMEM, p.ctx, sm);
            }
        }
        GB();
        if (bid < 256) {
            const int og = bid & 7, ks = bid >> 3;
            dev_gemm(p.ctx, D, p.ca_oW + (size_t)L * D * D, D,
                     p.PA + (size_t)ks * B * D, D, og * 128, ks * 32, 1, sm);
        }
        GB();
        if (bid < B)
            dev_ln(p.PA, 32, p.ca_ob + (size_t)L * D, p.x,
                   p.ln2g + (size_t)L * D, p.ln2b + (size_t)L * D, p.x, bid, sm);
        GB();

        // FFN
        if (bid < 256) {
            const int og = bid & 31, ks = bid >> 5;
            dev_gemm(p.x, D, p.W1 + (size_t)L * DFF * D, D,
                     p.Pf1 + (size_t)ks * B * DFF, DFF, og * 128, ks * 128, 4, sm);
        }
        GB();
        if (bid < 256) {
            const int og = bid & 7, ks = bid >> 3;
            dev_gemm_psum(p.Pf1, 8, p.b1 + (size_t)L * DFF, true, DFF,
                          p.W2 + (size_t)L * D * DFF, DFF,
                          p.Pf2 + (size_t)ks * B * D, D, og * 128, ks * 128, 4, sm);
        }
        GB();
        {
            float* lnout = (L == NLAYER - 1) ? p.out : p.x;
            if (bid < B)
                dev_ln(p.Pf2, 32, p.b2 + (size_t)L * D, p.x,
                       p.ln3g + (size_t)L * D, p.ln3b + (size_t)L * D, lnout, bid, sm);
        }
        GB();
    }
#undef GB
}

// ---------------------------------------------------------------------------
extern "C" void kernel_launch(void* const* d_in, const int* in_sizes, int n_in,
                              void* d_out, int out_size, void* d_ws, size_t ws_size,
                              hipStream_t stream)
{
    hipMemsetAsync(d_ws, 0, 4096, stream);   // zero barrier counters (ws is poisoned)

    float* ws = (float*)d_ws;
    MP p;
    p.tgt   = (const float*)d_in[0];
    p.cache = (const float*)d_in[1];
    p.K0    = (const float*)d_in[2];
    p.V0    = (const float*)d_in[3];
    p.K_mem = (const float*)d_in[4];
    p.V_mem = (const float*)d_in[5];
    p.sa_W  = (const float*)d_in[6];
    p.sa_b  = (const float*)d_in[7];
    p.sa_oW = (const float*)d_in[8];
    p.sa_ob = (const float*)d_in[9];
    p.ca_qW = (const float*)d_in[10];
    p.ca_qb = (const float*)d_in[11];
    p.ca_oW = (const float*)d_in[12];
    p.ca_ob = (const float*)d_in[13];
    p.W1    = (const float*)d_in[14];
    p.b1    = (const float*)d_in[15];
    p.W2    = (const float*)d_in[16];
    p.b2    = (const float*)d_in[17];
    p.ln1g  = (const float*)d_in[18];
    p.ln1b  = (const float*)d_in[19];
    p.ln2g  = (const float*)d_in[20];
    p.ln2b  = (const float*)d_in[21];
    p.ln3g  = (const float*)d_in[22];
    p.ln3b  = (const float*)d_in[23];

    p.bar   = (unsigned*)d_ws;
    p.x     = ws + 1024;
    p.ctx   = p.x + 65536;
    p.u     = p.ctx + 65536;          // 1,048,576
    p.Pq    = p.u + 1048576;          // 1,048,576
    p.PA    = p.Pq + 1048576;         // 2,097,152
    p.Pqkv  = p.PA + 2097152;         // 3,145,728
    p.Pc    = p.Pqkv + 3145728;       // 524,288
    p.Pf1   = p.Pc + 524288;          // 2,097,152
    p.Pf2   = p.Pf1 + 2097152;        // 2,097,152
    p.wp8   = p.Pf2 + 2097152;        // 8,388,608
    p.sums8 = p.wp8 + 8388608;        // 8,192
    p.out   = (float*)d_out;

    mega<<<dim3(NBLK), dim3(256), 0, stream>>>(p);
}

// Round 6
// 2713.304 us; speedup vs baseline: 2.3788x; 2.3788x over previous
//
#include <hip/hip_runtime.h>
#include <math.h>

#define B 64
#define D 1024
#define H 16
#define DH 64
#define T 511
#define TT 512          // T+1
#define SMEM 256
#define DFF 4096
#define NLAYER 4
#define SCALE 0.125f
#define EPS 1e-5f
#define NBLK 512

__device__ __forceinline__ float dot4(const float4 a, const float4 b) {
    return a.x * b.x + a.y * b.y + a.z * b.z + a.w * b.w;
}
__device__ __forceinline__ float4 f4add(float4 a, float4 b) {
    return make_float4(a.x + b.x, a.y + b.y, a.z + b.z, a.w + b.w);
}

struct MP {
    const float *tgt, *cache, *K0, *V0, *K_mem, *V_mem;
    const float *sa_W, *sa_b, *sa_oW, *sa_ob, *ca_qW, *ca_qb, *ca_oW, *ca_ob;
    const float *W1, *b1, *W2, *b2, *ln1g, *ln1b, *ln2g, *ln2b, *ln3g, *ln3b;
    float *x, *ctx, *u, *Pq, *PA, *Pqkv, *Pc, *Pf1, *Pf2, *wp8, *sums8;
    unsigned *bar;
    float *out;
};

// ---------------------------------------------------------------------------
// Two-level grid barrier (16 groups x 32 blocks -> root), sense by parity.
// Arrive: device fence (release, writes back L2) + hierarchical atomicAdd.
// Wait: RELAXED agent-scope polling (plain coherent load, NO cache
// invalidate per poll) + one acquire fence after the generation advances.
// The round-4 version polled with ACQUIRE => buffer_inv storm from idle
// blocks wiped L1/L2 continuously (VALUBusy 2.5%, 115us/barrier).
// ---------------------------------------------------------------------------
__device__ void gridbar(unsigned* bar, unsigned target) {
    __syncthreads();
    if (threadIdx.x == 0) {
        const unsigned par = target & 1u;
        unsigned* gen = bar;
        unsigned* cr  = bar + 16 + par * 16;
        unsigned* cg  = bar + 64 + par * 256 + (blockIdx.x & 15) * 16;
        __threadfence();
        if (atomicAdd(cg, 1u) == 31u) {
            if (atomicAdd(cr, 1u) == 15u) {
                #pragma unroll
                for (int i = 0; i < 16; ++i)
                    bar[64 + par * 256 + i * 16] = 0u;
                bar[16 + par * 16] = 0u;
                __threadfence();
                atomicAdd(gen, 1u);
            }
        }
        while (__hip_atomic_load(gen, __ATOMIC_RELAXED,
                                 __HIP_MEMORY_SCOPE_AGENT) < target)
            __builtin_amdgcn_s_sleep(4);
        __threadfence();
    }
    __syncthreads();
}

// ---------------------------------------------------------------------------
// GEMM tile: partial [64 b][128 o] for k in [kb, kb+nchunk*32). Thread 4b x 8o.
// ---------------------------------------------------------------------------
__device__ void dev_gemm(const float* __restrict__ A, int lda,
                         const float* __restrict__ W, int ldw,
                         float* __restrict__ Pout, int O,
                         int obase, int kb, int nchunk, float* sm)
{
    float* As = sm;             // [32][68]
    float* Ws = sm + 32 * 68;   // [32][132]
    const int tid = threadIdx.x;
    const int b0 = (tid >> 4) * 4;
    const int o0 = (tid & 15) * 8;
    float acc[4][8];
#pragma unroll
    for (int i = 0; i < 4; ++i)
#pragma unroll
        for (int j = 0; j < 8; ++j) acc[i][j] = 0.f;

    for (int c = 0; c < nchunk; ++c) {
        const int kc = kb + c * 32;
#pragma unroll
        for (int j = 0; j < 2; ++j) {
            const int f = tid + 256 * j;
            const int bb = f >> 3, k4 = f & 7;
            const float4 v = *(const float4*)(A + (size_t)bb * lda + kc + 4 * k4);
            As[(4 * k4 + 0) * 68 + bb] = v.x; As[(4 * k4 + 1) * 68 + bb] = v.y;
            As[(4 * k4 + 2) * 68 + bb] = v.z; As[(4 * k4 + 3) * 68 + bb] = v.w;
        }
#pragma unroll
        for (int j = 0; j < 4; ++j) {
            const int f = tid + 256 * j;
            const int oo = f >> 3, k4 = f & 7;
            const float4 v = *(const float4*)(W + (size_t)(obase + oo) * ldw + kc + 4 * k4);
            Ws[(4 * k4 + 0) * 132 + oo] = v.x; Ws[(4 * k4 + 1) * 132 + oo] = v.y;
            Ws[(4 * k4 + 2) * 132 + oo] = v.z; Ws[(4 * k4 + 3) * 132 + oo] = v.w;
        }
        __syncthreads();
#pragma unroll 8
        for (int k = 0; k < 32; ++k) {
            const float4 av = *(const float4*)(As + k * 68 + b0);
            const float4 w0 = *(const float4*)(Ws + k * 132 + o0);
            const float4 w1 = *(const float4*)(Ws + k * 132 + o0 + 4);
            const float a[4] = {av.x, av.y, av.z, av.w};
            const float w[8] = {w0.x, w0.y, w0.z, w0.w, w1.x, w1.y, w1.z, w1.w};
#pragma unroll
            for (int i = 0; i < 4; ++i)
#pragma unroll
                for (int j = 0; j < 8; ++j)
                    acc[i][j] = fmaf(a[i], w[j], acc[i][j]);
        }
        __syncthreads();
    }
#pragma unroll
    for (int i = 0; i < 4; ++i) {
        const float4 v0 = make_float4(acc[i][0], acc[i][1], acc[i][2], acc[i][3]);
        const float4 v1 = make_float4(acc[i][4], acc[i][5], acc[i][6], acc[i][7]);
        *(float4*)(Pout + (size_t)(b0 + i) * O + obase + o0) = v0;
        *(float4*)(Pout + (size_t)(b0 + i) * O + obase + o0 + 4) = v1;
    }
}

// ---------------------------------------------------------------------------
// GEMM with A = act(abias + sum of npart partials). Same tiling.
// ---------------------------------------------------------------------------
__device__ void dev_gemm_psum(const float* __restrict__ Pa, int npart,
                              const float* __restrict__ abias, bool relu, int Ka,
                              const float* __restrict__ W, int ldw,
                              float* __restrict__ Pout, int O,
                              int obase, int kb, int nchunk, float* sm)
{
    float* As = sm;
    float* Ws = sm + 32 * 68;
    const int tid = threadIdx.x;
    const int b0 = (tid >> 4) * 4;
    const int o0 = (tid & 15) * 8;
    float acc[4][8];
#pragma unroll
    for (int i = 0; i < 4; ++i)
#pragma unroll
        for (int j = 0; j < 8; ++j) acc[i][j] = 0.f;

    for (int c = 0; c < nchunk; ++c) {
        const int kc = kb + c * 32;
#pragma unroll
        for (int j = 0; j < 2; ++j) {
            const int f = tid + 256 * j;
            const int bb = f >> 3, k4 = f & 7;
            const int kg = kc + 4 * k4;
            float4 v = *(const float4*)(abias + kg);
            for (int s = 0; s < npart; ++s)
                v = f4add(v, *(const float4*)(Pa + (size_t)(s * 64 + bb) * Ka + kg));
            if (relu) {
                v.x = fmaxf(v.x, 0.f); v.y = fmaxf(v.y, 0.f);
                v.z = fmaxf(v.z, 0.f); v.w = fmaxf(v.w, 0.f);
            }
            As[(4 * k4 + 0) * 68 + bb] = v.x; As[(4 * k4 + 1) * 68 + bb] = v.y;
            As[(4 * k4 + 2) * 68 + bb] = v.z; As[(4 * k4 + 3) * 68 + bb] = v.w;
        }
#pragma unroll
        for (int j = 0; j < 4; ++j) {
            const int f = tid + 256 * j;
            const int oo = f >> 3, k4 = f & 7;
            const float4 v = *(const float4*)(W + (size_t)(obase + oo) * ldw + kc + 4 * k4);
            Ws[(4 * k4 + 0) * 132 + oo] = v.x; Ws[(4 * k4 + 1) * 132 + oo] = v.y;
            Ws[(4 * k4 + 2) * 132 + oo] = v.z; Ws[(4 * k4 + 3) * 132 + oo] = v.w;
        }
        __syncthreads();
#pragma unroll 8
        for (int k = 0; k < 32; ++k) {
            const float4 av = *(const float4*)(As + k * 68 + b0);
            const float4 w0 = *(const float4*)(Ws + k * 132 + o0);
            const float4 w1 = *(const float4*)(Ws + k * 132 + o0 + 4);
            const float a[4] = {av.x, av.y, av.z, av.w};
            const float w[8] = {w0.x, w0.y, w0.z, w0.w, w1.x, w1.y, w1.z, w1.w};
#pragma unroll
            for (int i = 0; i < 4; ++i)
#pragma unroll
                for (int j = 0; j < 8; ++j)
                    acc[i][j] = fmaf(a[i], w[j], acc[i][j]);
        }
        __syncthreads();
    }
#pragma unroll
    for (int i = 0; i < 4; ++i) {
        const float4 v0 = make_float4(acc[i][0], acc[i][1], acc[i][2], acc[i][3]);
        const float4 v1 = make_float4(acc[i][4], acc[i][5], acc[i][6], acc[i][7]);
        *(float4*)(Pout + (size_t)(b0 + i) * O + obase + o0) = v0;
        *(float4*)(Pout + (size_t)(b0 + i) * O + obase + o0 + 4) = v1;
    }
}

// ---------------------------------------------------------------------------
// u[b,h,dbase..+127] = sum_k q[b,h,k]*Wk[h*64+k][d]; q = sum 16 Pq + bq.
// ---------------------------------------------------------------------------
__device__ void dev_gemm_u(const float* __restrict__ Pq, const float* __restrict__ bq,
                           const float* __restrict__ Wk, int h, int dbase,
                           float* __restrict__ u, float* sm)
{
    float* As = sm;
    float* Ws = sm + 32 * 68;
    const int tid = threadIdx.x;
    const int b0 = (tid >> 4) * 4;
    const int o0 = (tid & 15) * 8;
    float acc[4][8];
#pragma unroll
    for (int i = 0; i < 4; ++i)
#pragma unroll
        for (int j = 0; j < 8; ++j) acc[i][j] = 0.f;

    for (int kc = 0; kc < DH; kc += 32) {
#pragma unroll
        for (int j = 0; j < 2; ++j) {
            const int f = tid + 256 * j;
            const int bb = f >> 3, k4 = f & 7;
            const int kg = h * DH + kc + 4 * k4;
            float4 v = *(const float4*)(bq + kg);
#pragma unroll
            for (int s = 0; s < 16; ++s)
                v = f4add(v, *(const float4*)(Pq + (size_t)(s * 64 + bb) * D + kg));
            As[(4 * k4 + 0) * 68 + bb] = v.x; As[(4 * k4 + 1) * 68 + bb] = v.y;
            As[(4 * k4 + 2) * 68 + bb] = v.z; As[(4 * k4 + 3) * 68 + bb] = v.w;
        }
#pragma unroll
        for (int j = 0; j < 4; ++j) {
            const int f = tid + 256 * j;
            const int k = f >> 5, d4 = f & 31;
            *(float4*)(Ws + k * 132 + 4 * d4) =
                *(const float4*)(Wk + (size_t)(h * DH + kc + k) * D + dbase + 4 * d4);
        }
        __syncthreads();
#pragma unroll 8
        for (int k = 0; k < 32; ++k) {
            const float4 av = *(const float4*)(As + k * 68 + b0);
            const float4 w0 = *(const float4*)(Ws + k * 132 + o0);
            const float4 w1 = *(const float4*)(Ws + k * 132 + o0 + 4);
            const float a[4] = {av.x, av.y, av.z, av.w};
            const float w[8] = {w0.x, w0.y, w0.z, w0.w, w1.x, w1.y, w1.z, w1.w};
#pragma unroll
            for (int i = 0; i < 4; ++i)
#pragma unroll
                for (int j = 0; j < 8; ++j)
                    acc[i][j] = fmaf(a[i], w[j], acc[i][j]);
        }
        __syncthreads();
    }
#pragma unroll
    for (int i = 0; i < 4; ++i) {
        const float4 v0 = make_float4(acc[i][0], acc[i][1], acc[i][2], acc[i][3]);
        const float4 v1 = make_float4(acc[i][4], acc[i][5], acc[i][6], acc[i][7]);
        float* ur = u + ((size_t)(b0 + i) * H + h) * D + dbase + o0;
        *(float4*)(ur) = v0;
        *(float4*)(ur + 4) = v1;
    }
}

// ---------------------------------------------------------------------------
// Streaming self-attn, 2 heads per 32-lane group. Block = (b, t8): 64 tokens.
// Lane owns d-indices {c*128 + seg*4 .. +3} (INTERLEAVED: lanes of a group
// read consecutive float4s => broadcast/conflict-free LDS; round-4's seg*32
// layout was a 32-way bank conflict, 1.13e8 conflict cycles).
// ---------------------------------------------------------------------------
__device__ void dev_sattn(const float* __restrict__ cache_i, const float* __restrict__ x,
                          const float* __restrict__ u, int b, int t8,
                          float* __restrict__ wp8, float* __restrict__ sums8, float* sm)
{
    const int tid = threadIdx.x;
    const int hp = tid >> 5;
    const int h0 = hp * 2, h1 = h0 + 1;
    const int seg = tid & 31;
    const int dof = seg * 4;

    float4 u0[8], u1[8], a0[8], a1[8];
    const float* ub0 = u + ((size_t)(b * H + h0)) * D;
    const float* ub1 = u + ((size_t)(b * H + h1)) * D;
#pragma unroll
    for (int c = 0; c < 8; ++c) {
        float4 v = *(const float4*)(ub0 + c * 128 + dof);
        u0[c] = make_float4(v.x * SCALE, v.y * SCALE, v.z * SCALE, v.w * SCALE);
        v = *(const float4*)(ub1 + c * 128 + dof);
        u1[c] = make_float4(v.x * SCALE, v.y * SCALE, v.z * SCALE, v.w * SCALE);
        a0[c] = make_float4(0.f, 0.f, 0.f, 0.f);
        a1[c] = make_float4(0.f, 0.f, 0.f, 0.f);
    }
    float s0 = 0.f, s1 = 0.f;

    float* rowb = sm;   // [2][2][1024]
    const int tg0 = t8 * 64;
    const int lr = tid >> 7;            // staged row 0/1
    const int lcf = (tid & 127) * 8;    // 8 floats per thread

    const float* r0p = (tg0 + lr < T) ? cache_i + ((size_t)(tg0 + lr) * B + b) * D
                                      : x + (size_t)b * D;
    float4 pa = *(const float4*)(r0p + lcf);
    float4 pb = *(const float4*)(r0p + lcf + 4);

    for (int st = 0; st < 32; ++st) {
        const int p = st & 1;
        *(float4*)(rowb + p * 2048 + lr * 1024 + lcf) = pa;
        *(float4*)(rowb + p * 2048 + lr * 1024 + lcf + 4) = pb;
        __syncthreads();
        if (st + 1 < 32) {
            const int t = tg0 + 2 * (st + 1) + lr;
            const float* rp = (t < T) ? cache_i + ((size_t)t * B + b) * D
                                      : x + (size_t)b * D;
            pa = *(const float4*)(rp + lcf);
            pb = *(const float4*)(rp + lcf + 4);
        }
#pragma unroll
        for (int r = 0; r < 2; ++r) {
            const float* rowp = rowb + p * 2048 + r * 1024;
            float4 rv[8];
            float d0 = 0.f, d1 = 0.f;
#pragma unroll
            for (int c = 0; c < 8; ++c) {
                rv[c] = *(const float4*)(rowp + c * 128 + dof);
                d0 += dot4(u0[c], rv[c]);
                d1 += dot4(u1[c], rv[c]);
            }
#pragma unroll
            for (int m = 16; m >= 1; m >>= 1) {
                d0 += __shfl_xor(d0, m, 64);
                d1 += __shfl_xor(d1, m, 64);
            }
            const float e0 = __expf(d0), e1 = __expf(d1);
            s0 += e0; s1 += e1;
#pragma unroll
            for (int c = 0; c < 8; ++c) {
                a0[c].x = fmaf(e0, rv[c].x, a0[c].x);
                a0[c].y = fmaf(e0, rv[c].y, a0[c].y);
                a0[c].z = fmaf(e0, rv[c].z, a0[c].z);
                a0[c].w = fmaf(e0, rv[c].w, a0[c].w);
                a1[c].x = fmaf(e1, rv[c].x, a1[c].x);
                a1[c].y = fmaf(e1, rv[c].y, a1[c].y);
                a1[c].z = fmaf(e1, rv[c].z, a1[c].z);
                a1[c].w = fmaf(e1, rv[c].w, a1[c].w);
            }
        }
    }

    float* w0 = wp8 + ((size_t)((b * 8 + t8) * H + h0)) * D;
    float* w1 = wp8 + ((size_t)((b * 8 + t8) * H + h1)) * D;
#pragma unroll
    for (int c = 0; c < 8; ++c) {
        *(float4*)(w0 + c * 128 + dof) = a0[c];
        *(float4*)(w1 + c * 128 + dof) = a1[c];
    }
    if (seg == 0) {
        sums8[(b * 8 + t8) * H + h0] = s0;
        sums8[(b * 8 + t8) * H + h1] = s1;
    }
}

// ---------------------------------------------------------------------------
// ctx partial (one k-slice of 128): A = (sum 8 wp8 partials) * (1/sumE).
// ---------------------------------------------------------------------------
__device__ void dev_gemm_ctx(const float* __restrict__ wp8, const float* __restrict__ sums8,
                             const float* __restrict__ Wv, int h, int kslice,
                             float* __restrict__ Pout, float* sm)
{
    float* As = sm;
    float* Ws = sm + 32 * 68;
    float* sinv = sm + 6400;
    const int tid = threadIdx.x;
    if (tid < 64) {
        float s = 0.f;
#pragma unroll
        for (int t = 0; t < 8; ++t) s += sums8[(tid * 8 + t) * H + h];
        sinv[tid] = 1.f / s;
    }
    __syncthreads();

    const int b0 = (tid >> 4) * 4;
    const int o0 = (tid & 15) * 4;
    float acc[4][4];
#pragma unroll
    for (int i = 0; i < 4; ++i)
#pragma unroll
        for (int j = 0; j < 4; ++j) acc[i][j] = 0.f;

    const int kb = kslice * 128;
    for (int kc = 0; kc < 128; kc += 32) {
#pragma unroll
        for (int j = 0; j < 2; ++j) {
            const int f = tid + 256 * j;
            const int bb = f >> 3, k4 = f & 7;
            const int kg = kb + kc + 4 * k4;
            float4 v = make_float4(0.f, 0.f, 0.f, 0.f);
#pragma unroll
            for (int t = 0; t < 8; ++t)
                v = f4add(v, *(const float4*)(wp8 + ((size_t)((bb * 8 + t) * H + h)) * D + kg));
            const float iv = sinv[bb];
            As[(4 * k4 + 0) * 68 + bb] = v.x * iv; As[(4 * k4 + 1) * 68 + bb] = v.y * iv;
            As[(4 * k4 + 2) * 68 + bb] = v.z * iv; As[(4 * k4 + 3) * 68 + bb] = v.w * iv;
        }
#pragma unroll
        for (int j = 0; j < 2; ++j) {
            const int f = tid + 256 * j;
            const int oo = f >> 3, k4 = f & 7;
            const float4 v = *(const float4*)(Wv + (size_t)(h * DH + oo) * D + kb + kc + 4 * k4);
            Ws[(4 * k4 + 0) * 68 + oo] = v.x; Ws[(4 * k4 + 1) * 68 + oo] = v.y;
            Ws[(4 * k4 + 2) * 68 + oo] = v.z; Ws[(4 * k4 + 3) * 68 + oo] = v.w;
        }
        __syncthreads();
#pragma unroll 8
        for (int k = 0; k < 32; ++k) {
            const float4 av = *(const float4*)(As + k * 68 + b0);
            const float4 wv = *(const float4*)(Ws + k * 68 + o0);
            const float a[4] = {av.x, av.y, av.z, av.w};
            const float w[4] = {wv.x, wv.y, wv.z, wv.w};
#pragma unroll
            for (int i = 0; i < 4; ++i)
#pragma unroll
                for (int j = 0; j < 4; ++j)
                    acc[i][j] = fmaf(a[i], w[j], acc[i][j]);
        }
        __syncthreads();
    }
#pragma unroll
    for (int i = 0; i < 4; ++i) {
        const float4 v = make_float4(acc[i][0], acc[i][1], acc[i][2], acc[i][3]);
        *(float4*)(Pout + (size_t)(b0 + i) * D + h * DH + o0) = v;
    }
}

// ---------------------------------------------------------------------------
// finish + residual + LayerNorm for row b.
// ---------------------------------------------------------------------------
__device__ void dev_ln(const float* __restrict__ Pp, int npart,
                       const float* __restrict__ bias, const float* __restrict__ resid,
                       const float* __restrict__ gg, const float* __restrict__ bbv,
                       float* __restrict__ out, int b, float* sm)
{
    float* red = sm;
    float* red2 = sm + 8;
    const int tid = threadIdx.x;
    float4 v = ((const float4*)bias)[tid];
    v = f4add(v, ((const float4*)(resid + (size_t)b * D))[tid]);
    for (int s = 0; s < npart; ++s)
        v = f4add(v, ((const float4*)Pp)[(size_t)(s * 64 + b) * 256 + tid]);

    float ssum = v.x + v.y + v.z + v.w;
#pragma unroll
    for (int m = 32; m >= 1; m >>= 1) ssum += __shfl_xor(ssum, m, 64);
    if ((tid & 63) == 0) red[tid >> 6] = ssum;
    __syncthreads();
    const float mean = (red[0] + red[1] + red[2] + red[3]) * (1.f / D);
    const float dx = v.x - mean, dy = v.y - mean, dz = v.z - mean, dw = v.w - mean;
    float q = dx * dx + dy * dy + dz * dz + dw * dw;
#pragma unroll
    for (int m = 32; m >= 1; m >>= 1) q += __shfl_xor(q, m, 64);
    if ((tid & 63) == 0) red2[tid >> 6] = q;
    __syncthreads();
    const float var = (red2[0] + red2[1] + red2[2] + red2[3]) * (1.f / D);
    const float rs = rsqrtf(var + EPS);
    const float4 gv = ((const float4*)gg)[tid];
    const float4 bv = ((const float4*)bbv)[tid];
    float4 o;
    o.x = dx * rs * gv.x + bv.x;
    o.y = dy * rs * gv.y + bv.y;
    o.z = dz * rs * gv.z + bv.z;
    o.w = dw * rs * gv.w + bv.w;
    ((float4*)(out + (size_t)b * D))[tid] = o;
}

// ---------------------------------------------------------------------------
// Fused attention for one (b,h). q (and HASX k/v extra row) from partials.
// ---------------------------------------------------------------------------
template <int NS, bool HASX>
__device__ void dev_attn(const float* __restrict__ qP, const float* __restrict__ qbias,
                         int npart, int qpitch, int b, int h,
                         const float* __restrict__ Kb, const float* __restrict__ Vb,
                         int nk, float* __restrict__ ctx, float* sm)
{
    float* qs = sm;
    float* kx = sm + 64;
    float* vx = sm + 128;
    float* r1 = sm + 192;
    float* r2 = sm + 200;
    float* sa = sm + 256;          // NS
    float* red = sm + 768;         // 1088 floats; also q-build partials
    const int tid = threadIdx.x;
    __syncthreads();   // protect sm reuse across consecutive calls

    {
        const int grp = tid >> 6, col = tid & 63;
        const int np4 = npart >> 2;
        const int colg = h * DH + col;
        float aq = 0.f, ak = 0.f, av = 0.f;
        for (int s = grp * np4; s < (grp + 1) * np4; ++s) {
            const float* base = qP + (size_t)(s * 64 + b) * qpitch + colg;
            aq += base[0];
            if (HASX) { ak += base[D]; av += base[2 * D]; }
        }
        red[grp * 64 + col] = aq;
        if (HASX) {
            red[256 + grp * 64 + col] = ak;
            red[512 + grp * 64 + col] = av;
        }
        __syncthreads();
        if (tid < 64) {
            qs[tid] = qbias[h * DH + tid] + red[tid] + red[64 + tid] +
                      red[128 + tid] + red[192 + tid];
            if (HASX) {
                kx[tid] = qbias[D + h * DH + tid] + red[256 + tid] + red[320 + tid] +
                          red[384 + tid] + red[448 + tid];
                vx[tid] = qbias[2 * D + h * DH + tid] + red[512 + tid] + red[576 + tid] +
                          red[640 + tid] + red[704 + tid];
            }
        }
        __syncthreads();
    }

    const int ss = tid >> 2, pp = tid & 3;
    const float* Kbh = Kb + ((size_t)(b * H + h)) * nk * DH;
#pragma unroll 2
    for (int pass = 0; pass < NS / 64; ++pass) {
        const int s = pass * 64 + ss;
        const float* row = (!HASX || s < nk) ? (Kbh + (size_t)s * DH) : kx;
        const float4* rp = (const float4*)row;
        const float4* qp = (const float4*)qs;
        float acc = 0.f;
#pragma unroll
        for (int c = 0; c < 4; ++c) acc += dot4(rp[pp * 4 + c], qp[pp * 4 + c]);
        acc += __shfl_xor(acc, 1, 64);
        acc += __shfl_xor(acc, 2, 64);
        if (pp == 0) sa[s] = acc * SCALE;
    }
    __syncthreads();

    float m = -1e30f;
    for (int k = tid; k < NS; k += 256) m = fmaxf(m, sa[k]);
#pragma unroll
    for (int mm = 32; mm >= 1; mm >>= 1) m = fmaxf(m, __shfl_xor(m, mm, 64));
    if ((tid & 63) == 0) r1[tid >> 6] = m;
    __syncthreads();
    m = fmaxf(fmaxf(r1[0], r1[1]), fmaxf(r1[2], r1[3]));
    float sum = 0.f;
    for (int k = tid; k < NS; k += 256) {
        const float e = __expf(sa[k] - m);
        sa[k] = e;
        sum += e;
    }
#pragma unroll
    for (int mm = 32; mm >= 1; mm >>= 1) sum += __shfl_xor(sum, mm, 64);
    if ((tid & 63) == 0) r2[tid >> 6] = sum;
    __syncthreads();
    const float inv = 1.f / (r2[0] + r2[1] + r2[2] + r2[3]);

    const int dh4 = tid & 15, sq = tid >> 4;
    const float* Vbh = Vb + ((size_t)(b * H + h)) * nk * DH;
    float4 acc = make_float4(0.f, 0.f, 0.f, 0.f);
#pragma unroll 2
    for (int s = sq; s < NS; s += 16) {
        const float* row = (!HASX || s < nk) ? (Vbh + (size_t)s * DH) : vx;
        const float4 vv = *(const float4*)(row + dh4 * 4);
        const float aw = sa[s];
        acc.x += aw * vv.x; acc.y += aw * vv.y;
        acc.z += aw * vv.z; acc.w += aw * vv.w;
    }
    __syncthreads();
    *(float4*)(red + sq * 68 + dh4 * 4) = acc;
    __syncthreads();
    if (tid < 64) {
        float t = 0.f;
#pragma unroll
        for (int k = 0; k < 16; ++k) t += red[k * 68 + tid];
        ctx[(size_t)b * D + h * DH + tid] = t * inv;
    }
}

// ---------------------------------------------------------------------------
__global__ __launch_bounds__(256, 2) void mega(MP p)
{
    __shared__ float sm[6496];
    const int bid = blockIdx.x;
    unsigned bt = 0;
#define GB() do { ++bt; gridbar(p.bar, bt); } while (0)

    for (int L = 0; L < NLAYER; ++L) {
        const float* Wqkv = p.sa_W + (size_t)L * 3 * D * D;
        const float* bqkv = p.sa_b + (size_t)L * 3 * D;
        const float* xin = (L == 0) ? p.tgt : p.x;

        if (L == 0) {
            if (bid < 384) {
                const int og = bid % 24, ks = bid / 24;
                dev_gemm(p.tgt, D, Wqkv, D, p.Pqkv + (size_t)ks * B * 3 * D, 3 * D,
                         og * 128, ks * 64, 2, sm);
            }
            GB();
#pragma unroll 1
            for (int j = 0; j < 2; ++j) {
                const int pair = bid * 2 + j;
                dev_attn<TT, true>(p.Pqkv, bqkv, 16, 3 * D, pair >> 4, pair & 15,
                                   p.K0, p.V0, T, p.ctx, sm);
            }
            GB();
            if (bid < 256) {
                const int og = bid & 7, ks = bid >> 3;
                dev_gemm(p.ctx, D, p.sa_oW, D, p.PA + (size_t)ks * B * D, D,
                         og * 128, ks * 32, 1, sm);
            }
            GB();
        } else {
            const float* cache_i = p.cache + (size_t)L * T * B * D;
            if (bid < 128) {
                const int og = bid & 7, ks = bid >> 3;
                dev_gemm(p.x, D, Wqkv, D, p.Pq + (size_t)ks * B * D, D,
                         og * 128, ks * 64, 2, sm);
            }
            GB();
            if (bid < 128)
                dev_gemm_u(p.Pq, bqkv, Wqkv + (size_t)D * D, bid >> 3,
                           (bid & 7) * 128, p.u, sm);
            GB();
            dev_sattn(cache_i, p.x, p.u, bid >> 3, bid & 7, p.wp8, p.sums8, sm);
            GB();
            if (bid < 128)
                dev_gemm_ctx(p.wp8, p.sums8, Wqkv + (size_t)2 * D * D, bid >> 3,
                             bid & 7, p.Pc + (size_t)(bid & 7) * B * D, sm);
            GB();
            if (bid < 256) {
                const int og = bid & 7, ks = bid >> 3;
                dev_gemm_psum(p.Pc, 8, bqkv + 2 * D, false, D,
                              p.sa_oW + (size_t)L * D * D, D,
                              p.PA + (size_t)ks * B * D, D, og * 128, ks * 32, 1, sm);
            }
            GB();
        }

        if (bid < B)
            dev_ln(p.PA, 32, p.sa_ob + (size_t)L * D, xin,
                   p.ln1g + (size_t)L * D, p.ln1b + (size_t)L * D, p.x, bid, sm);
        GB();

        // cross attention
        if (bid < 256) {
            const int og = bid & 7, ks = bid >> 3;
            dev_gemm(p.x, D, p.ca_qW + (size_t)L * D * D, D,
                     p.PA + (size_t)ks * B * D, D, og * 128, ks * 32, 1, sm);
        }
        GB();
        {
            const float* Kc = p.K_mem + (size_t)L * B * H * SMEM * DH;
            const float* Vc = p.V_mem + (size_t)L * B * H * SMEM * DH;
#pragma unroll 1
            for (int j = 0; j < 2; ++j) {
                const int pair = bid * 2 + j;
                dev_attn<SMEM, false>(p.PA, p.ca_qb + (size_t)L * D, 32, D,
                                      pair >> 4, pair & 15, Kc, Vc, SMEM, p.ctx, sm);
            }
        }
        GB();
        if (bid < 256) {
            const int og = bid & 7, ks = bid >> 3;
            dev_gemm(p.ctx, D, p.ca_oW + (size_t)L * D * D, D,
                     p.PA + (size_t)ks * B * D, D, og * 128, ks * 32, 1, sm);
        }
        GB();
        if (bid < B)
            dev_ln(p.PA, 32, p.ca_ob + (size_t)L * D, p.x,
                   p.ln2g + (size_t)L * D, p.ln2b + (size_t)L * D, p.x, bid, sm);
        GB();

        // FFN
        if (bid < 256) {
            const int og = bid & 31, ks = bid >> 5;
            dev_gemm(p.x, D, p.W1 + (size_t)L * DFF * D, D,
                     p.Pf1 + (size_t)ks * B * DFF, DFF, og * 128, ks * 128, 4, sm);
        }
        GB();
        if (bid < 256) {
            const int og = bid & 7, ks = bid >> 3;
            dev_gemm_psum(p.Pf1, 8, p.b1 + (size_t)L * DFF, true, DFF,
                          p.W2 + (size_t)L * D * DFF, DFF,
                          p.Pf2 + (size_t)ks * B * D, D, og * 128, ks * 128, 4, sm);
        }
        GB();
        {
            float* lnout = (L == NLAYER - 1) ? p.out : p.x;
            if (bid < B)
                dev_ln(p.Pf2, 32, p.b2 + (size_t)L * D, p.x,
                       p.ln3g + (size_t)L * D, p.ln3b + (size_t)L * D, lnout, bid, sm);
        }
        GB();
    }
#undef GB
}

// ---------------------------------------------------------------------------
extern "C" void kernel_launch(void* const* d_in, const int* in_sizes, int n_in,
                              void* d_out, int out_size, void* d_ws, size_t ws_size,
                              hipStream_t stream)
{
    hipMemsetAsync(d_ws, 0, 4096, stream);   // zero barrier counters (ws is poisoned)

    float* ws = (float*)d_ws;
    MP p;
    p.tgt   = (const float*)d_in[0];
    p.cache = (const float*)d_in[1];
    p.K0    = (const float*)d_in[2];
    p.V0    = (const float*)d_in[3];
    p.K_mem = (const float*)d_in[4];
    p.V_mem = (const float*)d_in[5];
    p.sa_W  = (const float*)d_in[6];
    p.sa_b  = (const float*)d_in[7];
    p.sa_oW = (const float*)d_in[8];
    p.sa_ob = (const float*)d_in[9];
    p.ca_qW = (const float*)d_in[10];
    p.ca_qb = (const float*)d_in[11];
    p.ca_oW = (const float*)d_in[12];
    p.ca_ob = (const float*)d_in[13];
    p.W1    = (const float*)d_in[14];
    p.b1    = (const float*)d_in[15];
    p.W2    = (const float*)d_in[16];
    p.b2    = (const float*)d_in[17];
    p.ln1g  = (const float*)d_in[18];
    p.ln1b  = (const float*)d_in[19];
    p.ln2g  = (const float*)d_in[20];
    p.ln2b  = (const float*)d_in[21];
    p.ln3g  = (const float*)d_in[22];
    p.ln3b  = (const float*)d_in[23];

    p.bar   = (unsigned*)d_ws;
    p.x     = ws + 1024;
    p.ctx   = p.x + 65536;
    p.u     = p.ctx + 65536;          // 1,048,576
    p.Pq    = p.u + 1048576;          // 1,048,576
    p.PA    = p.Pq + 1048576;         // 2,097,152
    p.Pqkv  = p.PA + 2097152;         // 3,145,728
    p.Pc    = p.Pqkv + 3145728;       // 524,288
    p.Pf1   = p.Pc + 524288;          // 2,097,152
    p.Pf2   = p.Pf1 + 2097152;        // 2,097,152
    p.wp8   = p.Pf2 + 2097152;        // 8,388,608
    p.sums8 = p.wp8 + 8388608;        // 8,192
    p.out   = (float*)d_out;

    mega<<<dim3(NBLK), dim3(256), 0, stream>>>(p);
}

// Round 7
// 1696.711 us; speedup vs baseline: 3.8041x; 1.5992x over previous
//
#include <hip/hip_runtime.h>
#include <math.h>

#define B 64
#define D 1024
#define H 16
#define DH 64
#define T 511
#define TT 512          // T+1
#define SMEM 256
#define DFF 4096
#define NLAYER 4
#define SCALE 0.125f
#define EPS 1e-5f
#define NBLK 512

typedef unsigned long long u64;

__device__ __forceinline__ float dot4(const float4 a, const float4 b) {
    return a.x * b.x + a.y * b.y + a.z * b.z + a.w * b.w;
}
__device__ __forceinline__ float4 f4add(float4 a, float4 b) {
    return make_float4(a.x + b.x, a.y + b.y, a.z + b.z, a.w + b.w);
}

// ---------------------------------------------------------------------------
// Agent-coherent (LLC-level, L1/L2-bypassing) accessors for INTERMEDIATE
// buffers. These make cross-XCD data flow work with NO wbl2/inv fences:
// relaxed agent atomics operate at the coherence point directly.
// 16B = 2x8B atomic ops (HW supports 32/64-bit atomics only).
// ---------------------------------------------------------------------------
__device__ __forceinline__ float4 ldq4(const float* p) {
    u64 a = __hip_atomic_load((u64*)p,     __ATOMIC_RELAXED, __HIP_MEMORY_SCOPE_AGENT);
    u64 b = __hip_atomic_load((u64*)p + 1, __ATOMIC_RELAXED, __HIP_MEMORY_SCOPE_AGENT);
    float4 r;
    ((u64*)&r)[0] = a; ((u64*)&r)[1] = b;
    return r;
}
__device__ __forceinline__ void stq4(float* p, float4 v) {
    __hip_atomic_store((u64*)p,     ((u64*)&v)[0], __ATOMIC_RELAXED, __HIP_MEMORY_SCOPE_AGENT);
    __hip_atomic_store((u64*)p + 1, ((u64*)&v)[1], __ATOMIC_RELAXED, __HIP_MEMORY_SCOPE_AGENT);
}
__device__ __forceinline__ float ldq1(const float* p) {
    unsigned x = __hip_atomic_load((unsigned*)p, __ATOMIC_RELAXED, __HIP_MEMORY_SCOPE_AGENT);
    return __uint_as_float(x);
}
__device__ __forceinline__ void stq1(float* p, float v) {
    __hip_atomic_store((unsigned*)p, __float_as_uint(v), __ATOMIC_RELAXED, __HIP_MEMORY_SCOPE_AGENT);
}

struct MP {
    const float *tgt, *cache, *K0, *V0, *K_mem, *V_mem;
    const float *sa_W, *sa_b, *sa_oW, *sa_ob, *ca_qW, *ca_qb, *ca_oW, *ca_ob;
    const float *W1, *b1, *W2, *b2, *ln1g, *ln1b, *ln2g, *ln2b, *ln3g, *ln3b;
    float *x, *ctx, *u, *Pq, *PA, *Pqkv, *Pc, *Pf1, *Pf2, *wp8, *sums8;
    unsigned *bar;
    float *out;
};

// ---------------------------------------------------------------------------
// FENCE-FREE two-level grid barrier. All data movement is via agent-scope
// ops (above), so no wbl2/inv is needed: just drain vmcnt, count arrivals
// hierarchically (16 groups x 32), bump a generation, poll relaxed.
// Counters live on distinct 128B lines. Parity double-buffers the slots.
// ---------------------------------------------------------------------------
__device__ void gridbar(unsigned* bar, unsigned target) {
    asm volatile("s_waitcnt vmcnt(0)" ::: "memory");   // per-wave store drain
    __syncthreads();
    if (threadIdx.x == 0) {
        const unsigned par = target & 1u;
        unsigned* gen = bar;                                   // line 0
        unsigned* cr  = bar + 32 + par * 32;                   // root counter
        unsigned* cg  = bar + 128 + (par * 16 + (blockIdx.x & 15)) * 32;
        if (__hip_atomic_fetch_add(cg, 1u, __ATOMIC_RELAXED,
                                   __HIP_MEMORY_SCOPE_AGENT) == 31u) {
            __hip_atomic_store(cg, 0u, __ATOMIC_RELAXED, __HIP_MEMORY_SCOPE_AGENT);
            if (__hip_atomic_fetch_add(cr, 1u, __ATOMIC_RELAXED,
                                       __HIP_MEMORY_SCOPE_AGENT) == 15u) {
                __hip_atomic_store(cr, 0u, __ATOMIC_RELAXED, __HIP_MEMORY_SCOPE_AGENT);
                __hip_atomic_fetch_add(gen, 1u, __ATOMIC_RELAXED,
                                       __HIP_MEMORY_SCOPE_AGENT);
            }
        }
        while (__hip_atomic_load(gen, __ATOMIC_RELAXED,
                                 __HIP_MEMORY_SCOPE_AGENT) < target)
            __builtin_amdgcn_s_sleep(16);
    }
    __syncthreads();
}

// ---------------------------------------------------------------------------
// GEMM tile: partial [64 b][128 o] for k in [kb, kb+nchunk*32). Thread 4b x 8o.
// A = intermediate (agent loads). W = weights (cached loads).
// ---------------------------------------------------------------------------
__device__ void dev_gemm(const float* __restrict__ A, int lda,
                         const float* __restrict__ W, int ldw,
                         float* __restrict__ Pout, int O,
                         int obase, int kb, int nchunk, float* sm)
{
    float* As = sm;             // [32][68]
    float* Ws = sm + 32 * 68;   // [32][132]
    const int tid = threadIdx.x;
    const int b0 = (tid >> 4) * 4;
    const int o0 = (tid & 15) * 8;
    float acc[4][8];
#pragma unroll
    for (int i = 0; i < 4; ++i)
#pragma unroll
        for (int j = 0; j < 8; ++j) acc[i][j] = 0.f;

    for (int c = 0; c < nchunk; ++c) {
        const int kc = kb + c * 32;
#pragma unroll
        for (int j = 0; j < 2; ++j) {
            const int f = tid + 256 * j;
            const int bb = f >> 3, k4 = f & 7;
            const float4 v = ldq4(A + (size_t)bb * lda + kc + 4 * k4);
            As[(4 * k4 + 0) * 68 + bb] = v.x; As[(4 * k4 + 1) * 68 + bb] = v.y;
            As[(4 * k4 + 2) * 68 + bb] = v.z; As[(4 * k4 + 3) * 68 + bb] = v.w;
        }
#pragma unroll
        for (int j = 0; j < 4; ++j) {
            const int f = tid + 256 * j;
            const int oo = f >> 3, k4 = f & 7;
            const float4 v = *(const float4*)(W + (size_t)(obase + oo) * ldw + kc + 4 * k4);
            Ws[(4 * k4 + 0) * 132 + oo] = v.x; Ws[(4 * k4 + 1) * 132 + oo] = v.y;
            Ws[(4 * k4 + 2) * 132 + oo] = v.z; Ws[(4 * k4 + 3) * 132 + oo] = v.w;
        }
        __syncthreads();
#pragma unroll 8
        for (int k = 0; k < 32; ++k) {
            const float4 av = *(const float4*)(As + k * 68 + b0);
            const float4 w0 = *(const float4*)(Ws + k * 132 + o0);
            const float4 w1 = *(const float4*)(Ws + k * 132 + o0 + 4);
            const float a[4] = {av.x, av.y, av.z, av.w};
            const float w[8] = {w0.x, w0.y, w0.z, w0.w, w1.x, w1.y, w1.z, w1.w};
#pragma unroll
            for (int i = 0; i < 4; ++i)
#pragma unroll
                for (int j = 0; j < 8; ++j)
                    acc[i][j] = fmaf(a[i], w[j], acc[i][j]);
        }
        __syncthreads();
    }
#pragma unroll
    for (int i = 0; i < 4; ++i) {
        const float4 v0 = make_float4(acc[i][0], acc[i][1], acc[i][2], acc[i][3]);
        const float4 v1 = make_float4(acc[i][4], acc[i][5], acc[i][6], acc[i][7]);
        stq4(Pout + (size_t)(b0 + i) * O + obase + o0, v0);
        stq4(Pout + (size_t)(b0 + i) * O + obase + o0 + 4, v1);
    }
}

// ---------------------------------------------------------------------------
// GEMM with A = act(abias + sum of npart partials). Partials via agent loads.
// ---------------------------------------------------------------------------
__device__ void dev_gemm_psum(const float* __restrict__ Pa, int npart,
                              const float* __restrict__ abias, bool relu, int Ka,
                              const float* __restrict__ W, int ldw,
                              float* __restrict__ Pout, int O,
                              int obase, int kb, int nchunk, float* sm)
{
    float* As = sm;
    float* Ws = sm + 32 * 68;
    const int tid = threadIdx.x;
    const int b0 = (tid >> 4) * 4;
    const int o0 = (tid & 15) * 8;
    float acc[4][8];
#pragma unroll
    for (int i = 0; i < 4; ++i)
#pragma unroll
        for (int j = 0; j < 8; ++j) acc[i][j] = 0.f;

    for (int c = 0; c < nchunk; ++c) {
        const int kc = kb + c * 32;
#pragma unroll
        for (int j = 0; j < 2; ++j) {
            const int f = tid + 256 * j;
            const int bb = f >> 3, k4 = f & 7;
            const int kg = kc + 4 * k4;
            float4 v = *(const float4*)(abias + kg);
            for (int s = 0; s < npart; ++s)
                v = f4add(v, ldq4(Pa + (size_t)(s * 64 + bb) * Ka + kg));
            if (relu) {
                v.x = fmaxf(v.x, 0.f); v.y = fmaxf(v.y, 0.f);
                v.z = fmaxf(v.z, 0.f); v.w = fmaxf(v.w, 0.f);
            }
            As[(4 * k4 + 0) * 68 + bb] = v.x; As[(4 * k4 + 1) * 68 + bb] = v.y;
            As[(4 * k4 + 2) * 68 + bb] = v.z; As[(4 * k4 + 3) * 68 + bb] = v.w;
        }
#pragma unroll
        for (int j = 0; j < 4; ++j) {
            const int f = tid + 256 * j;
            const int oo = f >> 3, k4 = f & 7;
            const float4 v = *(const float4*)(W + (size_t)(obase + oo) * ldw + kc + 4 * k4);
            Ws[(4 * k4 + 0) * 132 + oo] = v.x; Ws[(4 * k4 + 1) * 132 + oo] = v.y;
            Ws[(4 * k4 + 2) * 132 + oo] = v.z; Ws[(4 * k4 + 3) * 132 + oo] = v.w;
        }
        __syncthreads();
#pragma unroll 8
        for (int k = 0; k < 32; ++k) {
            const float4 av = *(const float4*)(As + k * 68 + b0);
            const float4 w0 = *(const float4*)(Ws + k * 132 + o0);
            const float4 w1 = *(const float4*)(Ws + k * 132 + o0 + 4);
            const float a[4] = {av.x, av.y, av.z, av.w};
            const float w[8] = {w0.x, w0.y, w0.z, w0.w, w1.x, w1.y, w1.z, w1.w};
#pragma unroll
            for (int i = 0; i < 4; ++i)
#pragma unroll
                for (int j = 0; j < 8; ++j)
                    acc[i][j] = fmaf(a[i], w[j], acc[i][j]);
        }
        __syncthreads();
    }
#pragma unroll
    for (int i = 0; i < 4; ++i) {
        const float4 v0 = make_float4(acc[i][0], acc[i][1], acc[i][2], acc[i][3]);
        const float4 v1 = make_float4(acc[i][4], acc[i][5], acc[i][6], acc[i][7]);
        stq4(Pout + (size_t)(b0 + i) * O + obase + o0, v0);
        stq4(Pout + (size_t)(b0 + i) * O + obase + o0 + 4, v1);
    }
}

// ---------------------------------------------------------------------------
// u[b,h,dbase..+127] = sum_k q[b,h,k]*Wk[h*64+k][d]; q = sum 16 Pq + bq.
// ---------------------------------------------------------------------------
__device__ void dev_gemm_u(const float* __restrict__ Pq, const float* __restrict__ bq,
                           const float* __restrict__ Wk, int h, int dbase,
                           float* __restrict__ u, float* sm)
{
    float* As = sm;
    float* Ws = sm + 32 * 68;
    const int tid = threadIdx.x;
    const int b0 = (tid >> 4) * 4;
    const int o0 = (tid & 15) * 8;
    float acc[4][8];
#pragma unroll
    for (int i = 0; i < 4; ++i)
#pragma unroll
        for (int j = 0; j < 8; ++j) acc[i][j] = 0.f;

    for (int kc = 0; kc < DH; kc += 32) {
#pragma unroll
        for (int j = 0; j < 2; ++j) {
            const int f = tid + 256 * j;
            const int bb = f >> 3, k4 = f & 7;
            const int kg = h * DH + kc + 4 * k4;
            float4 v = *(const float4*)(bq + kg);
#pragma unroll
            for (int s = 0; s < 16; ++s)
                v = f4add(v, ldq4(Pq + (size_t)(s * 64 + bb) * D + kg));
            As[(4 * k4 + 0) * 68 + bb] = v.x; As[(4 * k4 + 1) * 68 + bb] = v.y;
            As[(4 * k4 + 2) * 68 + bb] = v.z; As[(4 * k4 + 3) * 68 + bb] = v.w;
        }
#pragma unroll
        for (int j = 0; j < 4; ++j) {
            const int f = tid + 256 * j;
            const int k = f >> 5, d4 = f & 31;
            *(float4*)(Ws + k * 132 + 4 * d4) =
                *(const float4*)(Wk + (size_t)(h * DH + kc + k) * D + dbase + 4 * d4);
        }
        __syncthreads();
#pragma unroll 8
        for (int k = 0; k < 32; ++k) {
            const float4 av = *(const float4*)(As + k * 68 + b0);
            const float4 w0 = *(const float4*)(Ws + k * 132 + o0);
            const float4 w1 = *(const float4*)(Ws + k * 132 + o0 + 4);
            const float a[4] = {av.x, av.y, av.z, av.w};
            const float w[8] = {w0.x, w0.y, w0.z, w0.w, w1.x, w1.y, w1.z, w1.w};
#pragma unroll
            for (int i = 0; i < 4; ++i)
#pragma unroll
                for (int j = 0; j < 8; ++j)
                    acc[i][j] = fmaf(a[i], w[j], acc[i][j]);
        }
        __syncthreads();
    }
#pragma unroll
    for (int i = 0; i < 4; ++i) {
        const float4 v0 = make_float4(acc[i][0], acc[i][1], acc[i][2], acc[i][3]);
        const float4 v1 = make_float4(acc[i][4], acc[i][5], acc[i][6], acc[i][7]);
        float* ur = u + ((size_t)(b0 + i) * H + h) * D + dbase + o0;
        stq4(ur, v0);
        stq4(ur + 4, v1);
    }
}

// ---------------------------------------------------------------------------
// Streaming self-attn, 2 heads per 32-lane group. Block = (b, t8): 64 tokens.
// cache rows: cached loads; x row (t=511) and u/wp8/sums: agent ops.
// ---------------------------------------------------------------------------
__device__ void dev_sattn(const float* __restrict__ cache_i, const float* __restrict__ x,
                          const float* __restrict__ u, int b, int t8,
                          float* __restrict__ wp8, float* __restrict__ sums8, float* sm)
{
    const int tid = threadIdx.x;
    const int hp = tid >> 5;
    const int h0 = hp * 2, h1 = h0 + 1;
    const int seg = tid & 31;
    const int dof = seg * 4;

    float4 u0[8], u1[8], a0[8], a1[8];
    const float* ub0 = u + ((size_t)(b * H + h0)) * D;
    const float* ub1 = u + ((size_t)(b * H + h1)) * D;
#pragma unroll
    for (int c = 0; c < 8; ++c) {
        float4 v = ldq4(ub0 + c * 128 + dof);
        u0[c] = make_float4(v.x * SCALE, v.y * SCALE, v.z * SCALE, v.w * SCALE);
        v = ldq4(ub1 + c * 128 + dof);
        u1[c] = make_float4(v.x * SCALE, v.y * SCALE, v.z * SCALE, v.w * SCALE);
        a0[c] = make_float4(0.f, 0.f, 0.f, 0.f);
        a1[c] = make_float4(0.f, 0.f, 0.f, 0.f);
    }
    float s0 = 0.f, s1 = 0.f;

    float* rowb = sm;   // [2][2][1024]
    const int tg0 = t8 * 64;
    const int lr = tid >> 7;            // staged row 0/1
    const int lcf = (tid & 127) * 8;    // 8 floats per thread

    auto loadrow = [&](int t, int off) -> float4 {
        if (t < T) return *(const float4*)(cache_i + ((size_t)t * B + b) * D + off);
        return ldq4(x + (size_t)b * D + off);
    };
    float4 pa = loadrow(tg0 + lr, lcf);
    float4 pb = loadrow(tg0 + lr, lcf + 4);

    for (int st = 0; st < 32; ++st) {
        const int p = st & 1;
        *(float4*)(rowb + p * 2048 + lr * 1024 + lcf) = pa;
        *(float4*)(rowb + p * 2048 + lr * 1024 + lcf + 4) = pb;
        __syncthreads();
        if (st + 1 < 32) {
            const int t = tg0 + 2 * (st + 1) + lr;
            pa = loadrow(t, lcf);
            pb = loadrow(t, lcf + 4);
        }
#pragma unroll
        for (int r = 0; r < 2; ++r) {
            const float* rowp = rowb + p * 2048 + r * 1024;
            float4 rv[8];
            float d0 = 0.f, d1 = 0.f;
#pragma unroll
            for (int c = 0; c < 8; ++c) {
                rv[c] = *(const float4*)(rowp + c * 128 + dof);
                d0 += dot4(u0[c], rv[c]);
                d1 += dot4(u1[c], rv[c]);
            }
#pragma unroll
            for (int m = 16; m >= 1; m >>= 1) {
                d0 += __shfl_xor(d0, m, 64);
                d1 += __shfl_xor(d1, m, 64);
            }
            const float e0 = __expf(d0), e1 = __expf(d1);
            s0 += e0; s1 += e1;
#pragma unroll
            for (int c = 0; c < 8; ++c) {
                a0[c].x = fmaf(e0, rv[c].x, a0[c].x);
                a0[c].y = fmaf(e0, rv[c].y, a0[c].y);
                a0[c].z = fmaf(e0, rv[c].z, a0[c].z);
                a0[c].w = fmaf(e0, rv[c].w, a0[c].w);
                a1[c].x = fmaf(e1, rv[c].x, a1[c].x);
                a1[c].y = fmaf(e1, rv[c].y, a1[c].y);
                a1[c].z = fmaf(e1, rv[c].z, a1[c].z);
                a1[c].w = fmaf(e1, rv[c].w, a1[c].w);
            }
        }
    }

    float* w0 = wp8 + ((size_t)((b * 8 + t8) * H + h0)) * D;
    float* w1 = wp8 + ((size_t)((b * 8 + t8) * H + h1)) * D;
#pragma unroll
    for (int c = 0; c < 8; ++c) {
        stq4(w0 + c * 128 + dof, a0[c]);
        stq4(w1 + c * 128 + dof, a1[c]);
    }
    if (seg == 0) {
        stq1(sums8 + (b * 8 + t8) * H + h0, s0);
        stq1(sums8 + (b * 8 + t8) * H + h1, s1);
    }
}

// ---------------------------------------------------------------------------
// ctx partial (one k-slice of 64): A = (sum 8 wp8 partials) * (1/sumE).
// grid usage: 256 blocks = (h, kslice of 16).
// ---------------------------------------------------------------------------
__device__ void dev_gemm_ctx(const float* __restrict__ wp8, const float* __restrict__ sums8,
                             const float* __restrict__ Wv, int h, int kslice,
                             float* __restrict__ Pout, float* sm)
{
    float* As = sm;
    float* Ws = sm + 32 * 68;
    float* sinv = sm + 6400;
    const int tid = threadIdx.x;
    if (tid < 64) {
        float s = 0.f;
#pragma unroll
        for (int t = 0; t < 8; ++t) s += ldq1(sums8 + (tid * 8 + t) * H + h);
        sinv[tid] = 1.f / s;
    }
    __syncthreads();

    const int b0 = (tid >> 4) * 4;
    const int o0 = (tid & 15) * 4;
    float acc[4][4];
#pragma unroll
    for (int i = 0; i < 4; ++i)
#pragma unroll
        for (int j = 0; j < 4; ++j) acc[i][j] = 0.f;

    const int kb = kslice * 64;
    for (int kc = 0; kc < 64; kc += 32) {
#pragma unroll
        for (int j = 0; j < 2; ++j) {
            const int f = tid + 256 * j;
            const int bb = f >> 3, k4 = f & 7;
            const int kg = kb + kc + 4 * k4;
            float4 v = make_float4(0.f, 0.f, 0.f, 0.f);
#pragma unroll
            for (int t = 0; t < 8; ++t)
                v = f4add(v, ldq4(wp8 + ((size_t)((bb * 8 + t) * H + h)) * D + kg));
            const float iv = sinv[bb];
            As[(4 * k4 + 0) * 68 + bb] = v.x * iv; As[(4 * k4 + 1) * 68 + bb] = v.y * iv;
            As[(4 * k4 + 2) * 68 + bb] = v.z * iv; As[(4 * k4 + 3) * 68 + bb] = v.w * iv;
        }
#pragma unroll
        for (int j = 0; j < 2; ++j) {
            const int f = tid + 256 * j;
            const int oo = f >> 3, k4 = f & 7;
            const float4 v = *(const float4*)(Wv + (size_t)(h * DH + oo) * D + kb + kc + 4 * k4);
            Ws[(4 * k4 + 0) * 68 + oo] = v.x; Ws[(4 * k4 + 1) * 68 + oo] = v.y;
            Ws[(4 * k4 + 2) * 68 + oo] = v.z; Ws[(4 * k4 + 3) * 68 + oo] = v.w;
        }
        __syncthreads();
#pragma unroll 8
        for (int k = 0; k < 32; ++k) {
            const float4 av = *(const float4*)(As + k * 68 + b0);
            const float4 wv = *(const float4*)(Ws + k * 68 + o0);
            const float a[4] = {av.x, av.y, av.z, av.w};
            const float w[4] = {wv.x, wv.y, wv.z, wv.w};
#pragma unroll
            for (int i = 0; i < 4; ++i)
#pragma unroll
                for (int j = 0; j < 4; ++j)
                    acc[i][j] = fmaf(a[i], w[j], acc[i][j]);
        }
        __syncthreads();
    }
#pragma unroll
    for (int i = 0; i < 4; ++i) {
        const float4 v = make_float4(acc[i][0], acc[i][1], acc[i][2], acc[i][3]);
        stq4(Pout + (size_t)(b0 + i) * D + h * DH + o0, v);
    }
}

// ---------------------------------------------------------------------------
// finish + residual + LayerNorm for row b.
// ---------------------------------------------------------------------------
__device__ void dev_ln(const float* __restrict__ Pp, int npart,
                       const float* __restrict__ bias, const float* __restrict__ resid,
                       const float* __restrict__ gg, const float* __restrict__ bbv,
                       float* __restrict__ out, int b, float* sm)
{
    float* red = sm;
    float* red2 = sm + 8;
    const int tid = threadIdx.x;
    float4 v = ((const float4*)bias)[tid];
    v = f4add(v, ldq4(resid + (size_t)b * D + tid * 4));
    for (int s = 0; s < npart; ++s)
        v = f4add(v, ldq4(Pp + (size_t)(s * 64 + b) * D + tid * 4));

    float ssum = v.x + v.y + v.z + v.w;
#pragma unroll
    for (int m = 32; m >= 1; m >>= 1) ssum += __shfl_xor(ssum, m, 64);
    if ((tid & 63) == 0) red[tid >> 6] = ssum;
    __syncthreads();
    const float mean = (red[0] + red[1] + red[2] + red[3]) * (1.f / D);
    const float dx = v.x - mean, dy = v.y - mean, dz = v.z - mean, dw = v.w - mean;
    float q = dx * dx + dy * dy + dz * dz + dw * dw;
#pragma unroll
    for (int m = 32; m >= 1; m >>= 1) q += __shfl_xor(q, m, 64);
    if ((tid & 63) == 0) red2[tid >> 6] = q;
    __syncthreads();
    const float var = (red2[0] + red2[1] + red2[2] + red2[3]) * (1.f / D);
    const float rs = rsqrtf(var + EPS);
    const float4 gv = ((const float4*)gg)[tid];
    const float4 bv = ((const float4*)bbv)[tid];
    float4 o;
    o.x = dx * rs * gv.x + bv.x;
    o.y = dy * rs * gv.y + bv.y;
    o.z = dz * rs * gv.z + bv.z;
    o.w = dw * rs * gv.w + bv.w;
    stq4(out + (size_t)b * D + tid * 4, o);
}

// ---------------------------------------------------------------------------
// Fused attention for one (b,h). q (and HASX k/v extra row) from partials.
// ---------------------------------------------------------------------------
template <int NS, bool HASX>
__device__ void dev_attn(const float* __restrict__ qP, const float* __restrict__ qbias,
                         int npart, int qpitch, int b, int h,
                         const float* __restrict__ Kb, const float* __restrict__ Vb,
                         int nk, float* __restrict__ ctx, float* sm)
{
    float* qs = sm;
    float* kx = sm + 64;
    float* vx = sm + 128;
    float* r1 = sm + 192;
    float* r2 = sm + 200;
    float* sa = sm + 256;          // NS
    float* red = sm + 768;         // 1088 floats; also q-build partials
    const int tid = threadIdx.x;
    __syncthreads();   // protect sm reuse across consecutive calls

    {
        const int grp = tid >> 6, col = tid & 63;
        const int np4 = npart >> 2;
        const int colg = h * DH + col;
        float aq = 0.f, ak = 0.f, av = 0.f;
        for (int s = grp * np4; s < (grp + 1) * np4; ++s) {
            const float* base = qP + (size_t)(s * 64 + b) * qpitch + colg;
            aq += ldq1(base);
            if (HASX) { ak += ldq1(base + D); av += ldq1(base + 2 * D); }
        }
        red[grp * 64 + col] = aq;
        if (HASX) {
            red[256 + grp * 64 + col] = ak;
            red[512 + grp * 64 + col] = av;
        }
        __syncthreads();
        if (tid < 64) {
            qs[tid] = qbias[h * DH + tid] + red[tid] + red[64 + tid] +
                      red[128 + tid] + red[192 + tid];
            if (HASX) {
                kx[tid] = qbias[D + h * DH + tid] + red[256 + tid] + red[320 + tid] +
                          red[384 + tid] + red[448 + tid];
                vx[tid] = qbias[2 * D + h * DH + tid] + red[512 + tid] + red[576 + tid] +
                          red[640 + tid] + red[704 + tid];
            }
        }
        __syncthreads();
    }

    const int ss = tid >> 2, pp = tid & 3;
    const float* Kbh = Kb + ((size_t)(b * H + h)) * nk * DH;
#pragma unroll 2
    for (int pass = 0; pass < NS / 64; ++pass) {
        const int s = pass * 64 + ss;
        const float* row = (!HASX || s < nk) ? (Kbh + (size_t)s * DH) : kx;
        const float4* rp = (const float4*)row;
        const float4* qp = (const float4*)qs;
        float acc = 0.f;
#pragma unroll
        for (int c = 0; c < 4; ++c) acc += dot4(rp[pp * 4 + c], qp[pp * 4 + c]);
        acc += __shfl_xor(acc, 1, 64);
        acc += __shfl_xor(acc, 2, 64);
        if (pp == 0) sa[s] = acc * SCALE;
    }
    __syncthreads();

    float m = -1e30f;
    for (int k = tid; k < NS; k += 256) m = fmaxf(m, sa[k]);
#pragma unroll
    for (int mm = 32; mm >= 1; mm >>= 1) m = fmaxf(m, __shfl_xor(m, mm, 64));
    if ((tid & 63) == 0) r1[tid >> 6] = m;
    __syncthreads();
    m = fmaxf(fmaxf(r1[0], r1[1]), fmaxf(r1[2], r1[3]));
    float sum = 0.f;
    for (int k = tid; k < NS; k += 256) {
        const float e = __expf(sa[k] - m);
        sa[k] = e;
        sum += e;
    }
#pragma unroll
    for (int mm = 32; mm >= 1; mm >>= 1) sum += __shfl_xor(sum, mm, 64);
    if ((tid & 63) == 0) r2[tid >> 6] = sum;
    __syncthreads();
    const float inv = 1.f / (r2[0] + r2[1] + r2[2] + r2[3]);

    const int dh4 = tid & 15, sq = tid >> 4;
    const float* Vbh = Vb + ((size_t)(b * H + h)) * nk * DH;
    float4 acc = make_float4(0.f, 0.f, 0.f, 0.f);
#pragma unroll 2
    for (int s = sq; s < NS; s += 16) {
        const float* row = (!HASX || s < nk) ? (Vbh + (size_t)s * DH) : vx;
        const float4 vv = *(const float4*)(row + dh4 * 4);
        const float aw = sa[s];
        acc.x += aw * vv.x; acc.y += aw * vv.y;
        acc.z += aw * vv.z; acc.w += aw * vv.w;
    }
    __syncthreads();
    *(float4*)(red + sq * 68 + dh4 * 4) = acc;
    __syncthreads();
    if (tid < 64) {
        float t = 0.f;
#pragma unroll
        for (int k = 0; k < 16; ++k) t += red[k * 68 + tid];
        stq1(ctx + (size_t)b * D + h * DH + tid, t * inv);
    }
}

// ---------------------------------------------------------------------------
__global__ __launch_bounds__(256, 2) void mega(MP p)
{
    __shared__ float sm[6496];
    const int bid = blockIdx.x;
    unsigned bt = 0;
#define GB() do { ++bt; gridbar(p.bar, bt); } while (0)

    for (int L = 0; L < NLAYER; ++L) {
        const float* Wqkv = p.sa_W + (size_t)L * 3 * D * D;
        const float* bqkv = p.sa_b + (size_t)L * 3 * D;
        const float* xin = (L == 0) ? p.tgt : p.x;

        if (L == 0) {
            if (bid < 384) {
                const int og = bid % 24, ks = bid / 24;
                dev_gemm(p.tgt, D, Wqkv, D, p.Pqkv + (size_t)ks * B * 3 * D, 3 * D,
                         og * 128, ks * 64, 2, sm);
            }
            GB();
#pragma unroll 1
            for (int j = 0; j < 2; ++j) {
                const int pair = bid * 2 + j;
                dev_attn<TT, true>(p.Pqkv, bqkv, 16, 3 * D, pair >> 4, pair & 15,
                                   p.K0, p.V0, T, p.ctx, sm);
            }
            GB();
            if (bid < 256) {
                const int og = bid & 7, ks = bid >> 3;
                dev_gemm(p.ctx, D, p.sa_oW, D, p.PA + (size_t)ks * B * D, D,
                         og * 128, ks * 32, 1, sm);
            }
            GB();
        } else {
            const float* cache_i = p.cache + (size_t)L * T * B * D;
            if (bid < 128) {
                const int og = bid & 7, ks = bid >> 3;
                dev_gemm(p.x, D, Wqkv, D, p.Pq + (size_t)ks * B * D, D,
                         og * 128, ks * 64, 2, sm);
            }
            GB();
            if (bid < 128)
                dev_gemm_u(p.Pq, bqkv, Wqkv + (size_t)D * D, bid >> 3,
                           (bid & 7) * 128, p.u, sm);
            GB();
            dev_sattn(cache_i, p.x, p.u, bid >> 3, bid & 7, p.wp8, p.sums8, sm);
            GB();
            if (bid < 256)
                dev_gemm_ctx(p.wp8, p.sums8, Wqkv + (size_t)2 * D * D, bid >> 4,
                             bid & 15, p.Pc + (size_t)(bid & 15) * B * D, sm);
            GB();
            if (bid < 256) {
                const int og = bid & 7, ks = bid >> 3;
                dev_gemm_psum(p.Pc, 16, bqkv + 2 * D, false, D,
                              p.sa_oW + (size_t)L * D * D, D,
                              p.PA + (size_t)ks * B * D, D, og * 128, ks * 32, 1, sm);
            }
            GB();
        }

        if (bid < B)
            dev_ln(p.PA, 32, p.sa_ob + (size_t)L * D, xin,
                   p.ln1g + (size_t)L * D, p.ln1b + (size_t)L * D, p.x, bid, sm);
        GB();

        // cross attention
        if (bid < 256) {
            const int og = bid & 7, ks = bid >> 3;
            dev_gemm(p.x, D, p.ca_qW + (size_t)L * D * D, D,
                     p.PA + (size_t)ks * B * D, D, og * 128, ks * 32, 1, sm);
        }
        GB();
        {
            const float* Kc = p.K_mem + (size_t)L * B * H * SMEM * DH;
            const float* Vc = p.V_mem + (size_t)L * B * H * SMEM * DH;
#pragma unroll 1
            for (int j = 0; j < 2; ++j) {
                const int pair = bid * 2 + j;
                dev_attn<SMEM, false>(p.PA, p.ca_qb + (size_t)L * D, 32, D,
                                      pair >> 4, pair & 15, Kc, Vc, SMEM, p.ctx, sm);
            }
        }
        GB();
        if (bid < 256) {
            const int og = bid & 7, ks = bid >> 3;
            dev_gemm(p.ctx, D, p.ca_oW + (size_t)L * D * D, D,
                     p.PA + (size_t)ks * B * D, D, og * 128, ks * 32, 1, sm);
        }
        GB();
        if (bid < B)
            dev_ln(p.PA, 32, p.ca_ob + (size_t)L * D, p.x,
                   p.ln2g + (size_t)L * D, p.ln2b + (size_t)L * D, p.x, bid, sm);
        GB();

        // FFN (512-block splits)
        {
            const int og = bid & 31, ks = bid >> 5;   // 32 x 16
            dev_gemm(p.x, D, p.W1 + (size_t)L * DFF * D, D,
                     p.Pf1 + (size_t)ks * B * DFF, DFF, og * 128, ks * 64, 2, sm);
        }
        GB();
        {
            const int og = bid & 7, ks = bid >> 3;    // 8 x 64
            dev_gemm_psum(p.Pf1, 16, p.b1 + (size_t)L * DFF, true, DFF,
                          p.W2 + (size_t)L * D * DFF, DFF,
                          p.Pf2 + (size_t)ks * B * D, D, og * 128, ks * 64, 2, sm);
        }
        GB();
        {
            float* lnout = (L == NLAYER - 1) ? p.out : p.x;
            if (bid < B)
                dev_ln(p.Pf2, 64, p.b2 + (size_t)L * D, p.x,
                       p.ln3g + (size_t)L * D, p.ln3b + (size_t)L * D, lnout, bid, sm);
        }
        GB();
    }
#undef GB
}

// ---------------------------------------------------------------------------
extern "C" void kernel_launch(void* const* d_in, const int* in_sizes, int n_in,
                              void* d_out, int out_size, void* d_ws, size_t ws_size,
                              hipStream_t stream)
{
    hipMemsetAsync(d_ws, 0, 16384, stream);   // zero barrier counters

    float* ws = (float*)d_ws;
    MP p;
    p.tgt   = (const float*)d_in[0];
    p.cache = (const float*)d_in[1];
    p.K0    = (const float*)d_in[2];
    p.V0    = (const float*)d_in[3];
    p.K_mem = (const float*)d_in[4];
    p.V_mem = (const float*)d_in[5];
    p.sa_W  = (const float*)d_in[6];
    p.sa_b  = (const float*)d_in[7];
    p.sa_oW = (const float*)d_in[8];
    p.sa_ob = (const float*)d_in[9];
    p.ca_qW = (const float*)d_in[10];
    p.ca_qb = (const float*)d_in[11];
    p.ca_oW = (const float*)d_in[12];
    p.ca_ob = (const float*)d_in[13];
    p.W1    = (const float*)d_in[14];
    p.b1    = (const float*)d_in[15];
    p.W2    = (const float*)d_in[16];
    p.b2    = (const float*)d_in[17];
    p.ln1g  = (const float*)d_in[18];
    p.ln1b  = (const float*)d_in[19];
    p.ln2g  = (const float*)d_in[20];
    p.ln2b  = (const float*)d_in[21];
    p.ln3g  = (const float*)d_in[22];
    p.ln3b  = (const float*)d_in[23];

    p.bar   = (unsigned*)d_ws;              // 4096 u32 = 16 KB
    float* base = ws + 4096;
    p.x     = base;                          // 65,536
    p.ctx   = p.x + 65536;                   // 65,536
    p.u     = p.ctx + 65536;                 // 1,048,576
    p.Pq    = p.u + 1048576;                 // 16*B*D = 1,048,576
    p.PA    = p.Pq + 1048576;                // 32*B*D = 2,097,152
    p.Pc    = p.PA + 2097152;                // 16*B*D = 1,048,576
    float* R = p.Pc + 1048576;               // time-shared region (8,388,608)
    p.wp8   = R;                             // 8*B*H*D   (self-attn phases)
    p.Pqkv  = R;                             // 16*B*3D   (L0 qkv phases)
    p.Pf1   = R;                             // 16*B*DFF  (FFN phases)
    p.Pf2   = R + 4194304;                   // 64*B*D
    p.sums8 = R + 8388608;                   // 8,192
    p.out   = (float*)d_out;

    mega<<<dim3(NBLK), dim3(256), 0, stream>>>(p);
}

// Round 8
// 1682.180 us; speedup vs baseline: 3.8369x; 1.0086x over previous
//
#include <hip/hip_runtime.h>
#include <math.h>

#define B 64
#define D 1024
#define H 16
#define DH 64
#define T 511
#define TT 512          // T+1
#define SMEM 256
#define DFF 4096
#define NLAYER 4
#define SCALE 0.125f
#define EPS 1e-5f
#define NBLK 512

typedef unsigned long long u64;

__device__ __forceinline__ float dot4(const float4 a, const float4 b) {
    return a.x * b.x + a.y * b.y + a.z * b.z + a.w * b.w;
}
__device__ __forceinline__ float4 f4add(float4 a, float4 b) {
    return make_float4(a.x + b.x, a.y + b.y, a.z + b.z, a.w + b.w);
}

// ---------------------------------------------------------------------------
// Agent-coherent (LLC-level) accessors for INTERMEDIATE buffers: relaxed
// agent atomics bypass the non-coherent per-XCD L2, so cross-XCD dataflow
// needs no wbl2/inv fences. All uses sit in compile-time-unrolled loops so
// the loads pipeline (one waitcnt), never a serial latency chain.
// ---------------------------------------------------------------------------
__device__ __forceinline__ float4 ldq4(const float* p) {
    u64 a = __hip_atomic_load((u64*)p,     __ATOMIC_RELAXED, __HIP_MEMORY_SCOPE_AGENT);
    u64 b = __hip_atomic_load((u64*)p + 1, __ATOMIC_RELAXED, __HIP_MEMORY_SCOPE_AGENT);
    float4 r;
    ((u64*)&r)[0] = a; ((u64*)&r)[1] = b;
    return r;
}
__device__ __forceinline__ void stq4(float* p, float4 v) {
    __hip_atomic_store((u64*)p,     ((u64*)&v)[0], __ATOMIC_RELAXED, __HIP_MEMORY_SCOPE_AGENT);
    __hip_atomic_store((u64*)p + 1, ((u64*)&v)[1], __ATOMIC_RELAXED, __HIP_MEMORY_SCOPE_AGENT);
}
__device__ __forceinline__ float ldq1(const float* p) {
    unsigned x = __hip_atomic_load((unsigned*)p, __ATOMIC_RELAXED, __HIP_MEMORY_SCOPE_AGENT);
    return __uint_as_float(x);
}
__device__ __forceinline__ void stq1(float* p, float v) {
    __hip_atomic_store((unsigned*)p, __float_as_uint(v), __ATOMIC_RELAXED, __HIP_MEMORY_SCOPE_AGENT);
}

struct MP {
    const float *tgt, *cache, *K0, *V0, *K_mem, *V_mem;
    const float *sa_W, *sa_b, *sa_oW, *sa_ob, *ca_qW, *ca_qb, *ca_oW, *ca_ob;
    const float *W1, *b1, *W2, *b2, *ln1g, *ln1b, *ln2g, *ln2b, *ln3g, *ln3b;
    float *x, *ctx, *q, *qkv, *u, *Pq, *PA, *Pqkv, *Pc, *Pf1, *Pf2, *h1, *wp8, *sums8;
    unsigned *bar;
    float *out;
};

// ---------------------------------------------------------------------------
// Fence-free two-level grid barrier (16 groups x 32 -> root), relaxed polls.
// ---------------------------------------------------------------------------
__device__ void gridbar(unsigned* bar, unsigned target) {
    asm volatile("s_waitcnt vmcnt(0)" ::: "memory");
    __syncthreads();
    if (threadIdx.x == 0) {
        const unsigned par = target & 1u;
        unsigned* gen = bar;
        unsigned* cr  = bar + 32 + par * 32;
        unsigned* cg  = bar + 128 + (par * 16 + (blockIdx.x & 15)) * 32;
        if (__hip_atomic_fetch_add(cg, 1u, __ATOMIC_RELAXED,
                                   __HIP_MEMORY_SCOPE_AGENT) == 31u) {
            __hip_atomic_store(cg, 0u, __ATOMIC_RELAXED, __HIP_MEMORY_SCOPE_AGENT);
            if (__hip_atomic_fetch_add(cr, 1u, __ATOMIC_RELAXED,
                                       __HIP_MEMORY_SCOPE_AGENT) == 15u) {
                __hip_atomic_store(cr, 0u, __ATOMIC_RELAXED, __HIP_MEMORY_SCOPE_AGENT);
                __hip_atomic_fetch_add(gen, 1u, __ATOMIC_RELAXED,
                                       __HIP_MEMORY_SCOPE_AGENT);
            }
        }
        while (__hip_atomic_load(gen, __ATOMIC_RELAXED,
                                 __HIP_MEMORY_SCOPE_AGENT) < target)
            __builtin_amdgcn_s_sleep(16);
    }
    __syncthreads();
}

// ---------------------------------------------------------------------------
// GEMM tile: partial [64 b][128 o] for k in [kb, kb+nchunk*32). Thread 4b x 8o.
// AGENT_A: A is an intermediate (agent loads); else cached (input).
// ---------------------------------------------------------------------------
template <bool AGENT_A>
__device__ void dev_gemm(const float* __restrict__ A, int lda,
                         const float* __restrict__ W, int ldw,
                         float* __restrict__ Pout, int O,
                         int obase, int kb, int nchunk, float* sm)
{
    float* As = sm;             // [32][68]
    float* Ws = sm + 32 * 68;   // [32][132]
    const int tid = threadIdx.x;
    const int b0 = (tid >> 4) * 4;
    const int o0 = (tid & 15) * 8;
    float acc[4][8];
#pragma unroll
    for (int i = 0; i < 4; ++i)
#pragma unroll
        for (int j = 0; j < 8; ++j) acc[i][j] = 0.f;

    for (int c = 0; c < nchunk; ++c) {
        const int kc = kb + c * 32;
#pragma unroll
        for (int j = 0; j < 2; ++j) {
            const int f = tid + 256 * j;
            const int bb = f >> 3, k4 = f & 7;
            const float* ap = A + (size_t)bb * lda + kc + 4 * k4;
            const float4 v = AGENT_A ? ldq4(ap) : *(const float4*)ap;
            As[(4 * k4 + 0) * 68 + bb] = v.x; As[(4 * k4 + 1) * 68 + bb] = v.y;
            As[(4 * k4 + 2) * 68 + bb] = v.z; As[(4 * k4 + 3) * 68 + bb] = v.w;
        }
#pragma unroll
        for (int j = 0; j < 4; ++j) {
            const int f = tid + 256 * j;
            const int oo = f >> 3, k4 = f & 7;
            const float4 v = *(const float4*)(W + (size_t)(obase + oo) * ldw + kc + 4 * k4);
            Ws[(4 * k4 + 0) * 132 + oo] = v.x; Ws[(4 * k4 + 1) * 132 + oo] = v.y;
            Ws[(4 * k4 + 2) * 132 + oo] = v.z; Ws[(4 * k4 + 3) * 132 + oo] = v.w;
        }
        __syncthreads();
#pragma unroll 8
        for (int k = 0; k < 32; ++k) {
            const float4 av = *(const float4*)(As + k * 68 + b0);
            const float4 w0 = *(const float4*)(Ws + k * 132 + o0);
            const float4 w1 = *(const float4*)(Ws + k * 132 + o0 + 4);
            const float a[4] = {av.x, av.y, av.z, av.w};
            const float w[8] = {w0.x, w0.y, w0.z, w0.w, w1.x, w1.y, w1.z, w1.w};
#pragma unroll
            for (int i = 0; i < 4; ++i)
#pragma unroll
                for (int j = 0; j < 8; ++j)
                    acc[i][j] = fmaf(a[i], w[j], acc[i][j]);
        }
        __syncthreads();
    }
#pragma unroll
    for (int i = 0; i < 4; ++i) {
        const float4 v0 = make_float4(acc[i][0], acc[i][1], acc[i][2], acc[i][3]);
        const float4 v1 = make_float4(acc[i][4], acc[i][5], acc[i][6], acc[i][7]);
        stq4(Pout + (size_t)(b0 + i) * O + obase + o0, v0);
        stq4(Pout + (size_t)(b0 + i) * O + obase + o0 + 4, v1);
    }
}

// ---------------------------------------------------------------------------
// finish: out[b][o] = act(bias[o] + sum_s P[s][b][o]). Unrolled partial loads.
// ---------------------------------------------------------------------------
template <int NPART, bool RELU, int O>
__device__ void dev_finish(const float* __restrict__ P,
                           const float* __restrict__ bias,
                           float* __restrict__ out)
{
    constexpr int OC = O / 4;
    const int e = blockIdx.x * 256 + threadIdx.x;
    const int oc = e % OC, b = e / OC;
    float4 v = ((const float4*)bias)[oc];
#pragma unroll
    for (int s = 0; s < NPART; ++s)
        v = f4add(v, ldq4(P + (size_t)(s * 64 + b) * O + oc * 4));
    if (RELU) {
        v.x = fmaxf(v.x, 0.f); v.y = fmaxf(v.y, 0.f);
        v.z = fmaxf(v.z, 0.f); v.w = fmaxf(v.w, 0.f);
    }
    stq4(out + (size_t)b * O + oc * 4, v);
}

// ---------------------------------------------------------------------------
// u[b,h,dbase..+127] = sum_k q[b,h,k]*Wk[h*64+k][d]; q materialized.
// ---------------------------------------------------------------------------
__device__ void dev_gemm_u(const float* __restrict__ q,
                           const float* __restrict__ Wk, int h, int dbase,
                           float* __restrict__ u, float* sm)
{
    float* As = sm;
    float* Ws = sm + 32 * 68;
    const int tid = threadIdx.x;
    const int b0 = (tid >> 4) * 4;
    const int o0 = (tid & 15) * 8;
    float acc[4][8];
#pragma unroll
    for (int i = 0; i < 4; ++i)
#pragma unroll
        for (int j = 0; j < 8; ++j) acc[i][j] = 0.f;

    for (int kc = 0; kc < DH; kc += 32) {
#pragma unroll
        for (int j = 0; j < 2; ++j) {
            const int f = tid + 256 * j;
            const int bb = f >> 3, k4 = f & 7;
            const float4 v = ldq4(q + (size_t)bb * D + h * DH + kc + 4 * k4);
            As[(4 * k4 + 0) * 68 + bb] = v.x; As[(4 * k4 + 1) * 68 + bb] = v.y;
            As[(4 * k4 + 2) * 68 + bb] = v.z; As[(4 * k4 + 3) * 68 + bb] = v.w;
        }
#pragma unroll
        for (int j = 0; j < 4; ++j) {
            const int f = tid + 256 * j;
            const int k = f >> 5, d4 = f & 31;
            *(float4*)(Ws + k * 132 + 4 * d4) =
                *(const float4*)(Wk + (size_t)(h * DH + kc + k) * D + dbase + 4 * d4);
        }
        __syncthreads();
#pragma unroll 8
        for (int k = 0; k < 32; ++k) {
            const float4 av = *(const float4*)(As + k * 68 + b0);
            const float4 w0 = *(const float4*)(Ws + k * 132 + o0);
            const float4 w1 = *(const float4*)(Ws + k * 132 + o0 + 4);
            const float a[4] = {av.x, av.y, av.z, av.w};
            const float w[8] = {w0.x, w0.y, w0.z, w0.w, w1.x, w1.y, w1.z, w1.w};
#pragma unroll
            for (int i = 0; i < 4; ++i)
#pragma unroll
                for (int j = 0; j < 8; ++j)
                    acc[i][j] = fmaf(a[i], w[j], acc[i][j]);
        }
        __syncthreads();
    }
#pragma unroll
    for (int i = 0; i < 4; ++i) {
        const float4 v0 = make_float4(acc[i][0], acc[i][1], acc[i][2], acc[i][3]);
        const float4 v1 = make_float4(acc[i][4], acc[i][5], acc[i][6], acc[i][7]);
        float* ur = u + ((size_t)(b0 + i) * H + h) * D + dbase + o0;
        stq4(ur, v0);
        stq4(ur + 4, v1);
    }
}

// ---------------------------------------------------------------------------
// Streaming self-attn, 2 heads per 32-lane group. Block = (b, t8): 64 tokens.
// Interleaved d-layout (seg*4): conflict-free LDS broadcast.
// ---------------------------------------------------------------------------
__device__ void dev_sattn(const float* __restrict__ cache_i, const float* __restrict__ x,
                          const float* __restrict__ u, int b, int t8,
                          float* __restrict__ wp8, float* __restrict__ sums8, float* sm)
{
    const int tid = threadIdx.x;
    const int hp = tid >> 5;
    const int h0 = hp * 2, h1 = h0 + 1;
    const int seg = tid & 31;
    const int dof = seg * 4;

    float4 u0[8], u1[8], a0[8], a1[8];
    const float* ub0 = u + ((size_t)(b * H + h0)) * D;
    const float* ub1 = u + ((size_t)(b * H + h1)) * D;
#pragma unroll
    for (int c = 0; c < 8; ++c) {
        float4 v = ldq4(ub0 + c * 128 + dof);
        u0[c] = make_float4(v.x * SCALE, v.y * SCALE, v.z * SCALE, v.w * SCALE);
        v = ldq4(ub1 + c * 128 + dof);
        u1[c] = make_float4(v.x * SCALE, v.y * SCALE, v.z * SCALE, v.w * SCALE);
        a0[c] = make_float4(0.f, 0.f, 0.f, 0.f);
        a1[c] = make_float4(0.f, 0.f, 0.f, 0.f);
    }
    float s0 = 0.f, s1 = 0.f;

    float* rowb = sm;   // [2][2][1024]
    const int tg0 = t8 * 64;
    const int lr = tid >> 7;
    const int lcf = (tid & 127) * 8;

    auto loadrow = [&](int t, int off) -> float4 {
        if (t < T) return *(const float4*)(cache_i + ((size_t)t * B + b) * D + off);
        return ldq4(x + (size_t)b * D + off);
    };
    float4 pa = loadrow(tg0 + lr, lcf);
    float4 pb = loadrow(tg0 + lr, lcf + 4);

    for (int st = 0; st < 32; ++st) {
        const int p = st & 1;
        *(float4*)(rowb + p * 2048 + lr * 1024 + lcf) = pa;
        *(float4*)(rowb + p * 2048 + lr * 1024 + lcf + 4) = pb;
        __syncthreads();
        if (st + 1 < 32) {
            const int t = tg0 + 2 * (st + 1) + lr;
            pa = loadrow(t, lcf);
            pb = loadrow(t, lcf + 4);
        }
#pragma unroll
        for (int r = 0; r < 2; ++r) {
            const float* rowp = rowb + p * 2048 + r * 1024;
            float4 rv[8];
            float d0 = 0.f, d1 = 0.f;
#pragma unroll
            for (int c = 0; c < 8; ++c) {
                rv[c] = *(const float4*)(rowp + c * 128 + dof);
                d0 += dot4(u0[c], rv[c]);
                d1 += dot4(u1[c], rv[c]);
            }
#pragma unroll
            for (int m = 16; m >= 1; m >>= 1) {
                d0 += __shfl_xor(d0, m, 64);
                d1 += __shfl_xor(d1, m, 64);
            }
            const float e0 = __expf(d0), e1 = __expf(d1);
            s0 += e0; s1 += e1;
#pragma unroll
            for (int c = 0; c < 8; ++c) {
                a0[c].x = fmaf(e0, rv[c].x, a0[c].x);
                a0[c].y = fmaf(e0, rv[c].y, a0[c].y);
                a0[c].z = fmaf(e0, rv[c].z, a0[c].z);
                a0[c].w = fmaf(e0, rv[c].w, a0[c].w);
                a1[c].x = fmaf(e1, rv[c].x, a1[c].x);
                a1[c].y = fmaf(e1, rv[c].y, a1[c].y);
                a1[c].z = fmaf(e1, rv[c].z, a1[c].z);
                a1[c].w = fmaf(e1, rv[c].w, a1[c].w);
            }
        }
    }

    float* w0 = wp8 + ((size_t)((b * 8 + t8) * H + h0)) * D;
    float* w1 = wp8 + ((size_t)((b * 8 + t8) * H + h1)) * D;
#pragma unroll
    for (int c = 0; c < 8; ++c) {
        stq4(w0 + c * 128 + dof, a0[c]);
        stq4(w1 + c * 128 + dof, a1[c]);
    }
    if (seg == 0) {
        stq1(sums8 + (b * 8 + t8) * H + h0, s0);
        stq1(sums8 + (b * 8 + t8) * H + h1, s1);
    }
}

// ---------------------------------------------------------------------------
// ctx partial (one k-slice of 64): A = (sum 8 wp8 partials) * (1/sumE).
// ---------------------------------------------------------------------------
__device__ void dev_gemm_ctx(const float* __restrict__ wp8, const float* __restrict__ sums8,
                             const float* __restrict__ Wv, int h, int kslice,
                             float* __restrict__ Pout, float* sm)
{
    float* As = sm;
    float* Ws = sm + 32 * 68;
    float* sinv = sm + 6400;
    const int tid = threadIdx.x;
    if (tid < 64) {
        float s = 0.f;
#pragma unroll
        for (int t = 0; t < 8; ++t) s += ldq1(sums8 + (tid * 8 + t) * H + h);
        sinv[tid] = 1.f / s;
    }
    __syncthreads();

    const int b0 = (tid >> 4) * 4;
    const int o0 = (tid & 15) * 4;
    float acc[4][4];
#pragma unroll
    for (int i = 0; i < 4; ++i)
#pragma unroll
        for (int j = 0; j < 4; ++j) acc[i][j] = 0.f;

    const int kb = kslice * 64;
    for (int kc = 0; kc < 64; kc += 32) {
#pragma unroll
        for (int j = 0; j < 2; ++j) {
            const int f = tid + 256 * j;
            const int bb = f >> 3, k4 = f & 7;
            const int kg = kb + kc + 4 * k4;
            float4 v = make_float4(0.f, 0.f, 0.f, 0.f);
#pragma unroll
            for (int t = 0; t < 8; ++t)
                v = f4add(v, ldq4(wp8 + ((size_t)((bb * 8 + t) * H + h)) * D + kg));
            const float iv = sinv[bb];
            As[(4 * k4 + 0) * 68 + bb] = v.x * iv; As[(4 * k4 + 1) * 68 + bb] = v.y * iv;
            As[(4 * k4 + 2) * 68 + bb] = v.z * iv; As[(4 * k4 + 3) * 68 + bb] = v.w * iv;
        }
#pragma unroll
        for (int j = 0; j < 2; ++j) {
            const int f = tid + 256 * j;
            const int oo = f >> 3, k4 = f & 7;
            const float4 v = *(const float4*)(Wv + (size_t)(h * DH + oo) * D + kb + kc + 4 * k4);
            Ws[(4 * k4 + 0) * 68 + oo] = v.x; Ws[(4 * k4 + 1) * 68 + oo] = v.y;
            Ws[(4 * k4 + 2) * 68 + oo] = v.z; Ws[(4 * k4 + 3) * 68 + oo] = v.w;
        }
        __syncthreads();
#pragma unroll 8
        for (int k = 0; k < 32; ++k) {
            const float4 av = *(const float4*)(As + k * 68 + b0);
            const float4 wv = *(const float4*)(Ws + k * 68 + o0);
            const float a[4] = {av.x, av.y, av.z, av.w};
            const float w[4] = {wv.x, wv.y, wv.z, wv.w};
#pragma unroll
            for (int i = 0; i < 4; ++i)
#pragma unroll
                for (int j = 0; j < 4; ++j)
                    acc[i][j] = fmaf(a[i], w[j], acc[i][j]);
        }
        __syncthreads();
    }
#pragma unroll
    for (int i = 0; i < 4; ++i) {
        const float4 v = make_float4(acc[i][0], acc[i][1], acc[i][2], acc[i][3]);
        stq4(Pout + (size_t)(b0 + i) * D + h * DH + o0, v);
    }
}

// ---------------------------------------------------------------------------
// finish + residual + LayerNorm for row b. NPART compile-time (pipelined).
// ---------------------------------------------------------------------------
template <int NPART>
__device__ void dev_ln(const float* __restrict__ Pp,
                       const float* __restrict__ bias, const float* __restrict__ resid,
                       const float* __restrict__ gg, const float* __restrict__ bbv,
                       float* __restrict__ out, int b, float* sm)
{
    float* red = sm;
    float* red2 = sm + 8;
    const int tid = threadIdx.x;
    float4 v = ((const float4*)bias)[tid];
    v = f4add(v, ldq4(resid + (size_t)b * D + tid * 4));
#pragma unroll
    for (int s = 0; s < NPART; ++s)
        v = f4add(v, ldq4(Pp + (size_t)(s * 64 + b) * D + tid * 4));

    float ssum = v.x + v.y + v.z + v.w;
#pragma unroll
    for (int m = 32; m >= 1; m >>= 1) ssum += __shfl_xor(ssum, m, 64);
    if ((tid & 63) == 0) red[tid >> 6] = ssum;
    __syncthreads();
    const float mean = (red[0] + red[1] + red[2] + red[3]) * (1.f / D);
    const float dx = v.x - mean, dy = v.y - mean, dz = v.z - mean, dw = v.w - mean;
    float q = dx * dx + dy * dy + dz * dz + dw * dw;
#pragma unroll
    for (int m = 32; m >= 1; m >>= 1) q += __shfl_xor(q, m, 64);
    if ((tid & 63) == 0) red2[tid >> 6] = q;
    __syncthreads();
    const float var = (red2[0] + red2[1] + red2[2] + red2[3]) * (1.f / D);
    const float rs = rsqrtf(var + EPS);
    const float4 gv = ((const float4*)gg)[tid];
    const float4 bv = ((const float4*)bbv)[tid];
    float4 o;
    o.x = dx * rs * gv.x + bv.x;
    o.y = dy * rs * gv.y + bv.y;
    o.z = dz * rs * gv.z + bv.z;
    o.w = dw * rs * gv.w + bv.w;
    stq4(out + (size_t)b * D + tid * 4, o);
}

// ---------------------------------------------------------------------------
// Fused attention for one (b,h).
// HASX (L0): q/k/v rows read from materialized qkv (pitch 3*D, bias applied).
// else: q built from 16 PA partials + bias (unrolled).
// ---------------------------------------------------------------------------
template <int NS, bool HASX>
__device__ void dev_attn(const float* __restrict__ qsrc, const float* __restrict__ qbias,
                         int b, int h,
                         const float* __restrict__ Kb, const float* __restrict__ Vb,
                         int nk, float* __restrict__ ctx, float* sm)
{
    float* qs = sm;
    float* kx = sm + 64;
    float* vx = sm + 128;
    float* r1 = sm + 192;
    float* r2 = sm + 200;
    float* sa = sm + 256;          // NS
    float* red = sm + 768;
    const int tid = threadIdx.x;
    __syncthreads();   // protect sm reuse across consecutive calls

    if (HASX) {
        if (tid < 64) {
            const float* base = qsrc + (size_t)b * 3 * D + h * DH + tid;
            qs[tid] = ldq1(base);
            kx[tid] = ldq1(base + D);
            vx[tid] = ldq1(base + 2 * D);
        }
        __syncthreads();
    } else {
        const int grp = tid >> 6, col = tid & 63;
        float a = 0.f;
#pragma unroll
        for (int s = 0; s < 4; ++s)
            a += ldq1(qsrc + (size_t)((grp * 4 + s) * 64 + b) * D + h * DH + col);
        red[grp * 64 + col] = a;
        __syncthreads();
        if (tid < 64)
            qs[tid] = qbias[h * DH + tid] + red[tid] + red[64 + tid] +
                      red[128 + tid] + red[192 + tid];
        __syncthreads();
    }

    const int ss = tid >> 2, pp = tid & 3;
    const float* Kbh = Kb + ((size_t)(b * H + h)) * nk * DH;
#pragma unroll 2
    for (int pass = 0; pass < NS / 64; ++pass) {
        const int s = pass * 64 + ss;
        const float* row = (!HASX || s < nk) ? (Kbh + (size_t)s * DH) : kx;
        const float4* rp = (const float4*)row;
        const float4* qp = (const float4*)qs;
        float acc = 0.f;
#pragma unroll
        for (int c = 0; c < 4; ++c) acc += dot4(rp[pp * 4 + c], qp[pp * 4 + c]);
        acc += __shfl_xor(acc, 1, 64);
        acc += __shfl_xor(acc, 2, 64);
        if (pp == 0) sa[s] = acc * SCALE;
    }
    __syncthreads();

    float m = -1e30f;
    for (int k = tid; k < NS; k += 256) m = fmaxf(m, sa[k]);
#pragma unroll
    for (int mm = 32; mm >= 1; mm >>= 1) m = fmaxf(m, __shfl_xor(m, mm, 64));
    if ((tid & 63) == 0) r1[tid >> 6] = m;
    __syncthreads();
    m = fmaxf(fmaxf(r1[0], r1[1]), fmaxf(r1[2], r1[3]));
    float sum = 0.f;
    for (int k = tid; k < NS; k += 256) {
        const float e = __expf(sa[k] - m);
        sa[k] = e;
        sum += e;
    }
#pragma unroll
    for (int mm = 32; mm >= 1; mm >>= 1) sum += __shfl_xor(sum, mm, 64);
    if ((tid & 63) == 0) r2[tid >> 6] = sum;
    __syncthreads();
    const float inv = 1.f / (r2[0] + r2[1] + r2[2] + r2[3]);

    const int dh4 = tid & 15, sq = tid >> 4;
    const float* Vbh = Vb + ((size_t)(b * H + h)) * nk * DH;
    float4 acc = make_float4(0.f, 0.f, 0.f, 0.f);
#pragma unroll 2
    for (int s = sq; s < NS; s += 16) {
        const float* row = (!HASX || s < nk) ? (Vbh + (size_t)s * DH) : vx;
        const float4 vv = *(const float4*)(row + dh4 * 4);
        const float aw = sa[s];
        acc.x += aw * vv.x; acc.y += aw * vv.y;
        acc.z += aw * vv.z; acc.w += aw * vv.w;
    }
    __syncthreads();
    *(float4*)(red + sq * 68 + dh4 * 4) = acc;
    __syncthreads();
    if (tid < 64) {
        float t = 0.f;
#pragma unroll
        for (int k = 0; k < 16; ++k) t += red[k * 68 + tid];
        stq1(ctx + (size_t)b * D + h * DH + tid, t * inv);
    }
}

// ---------------------------------------------------------------------------
__global__ __launch_bounds__(256, 2) void mega(MP p)
{
    __shared__ float sm[6496];
    const int bid = blockIdx.x;
    unsigned bt = 0;
#define GB() do { ++bt; gridbar(p.bar, bt); } while (0)

    for (int L = 0; L < NLAYER; ++L) {
        const float* Wqkv = p.sa_W + (size_t)L * 3 * D * D;
        const float* bqkv = p.sa_b + (size_t)L * 3 * D;
        const float* xin = (L == 0) ? p.tgt : p.x;

        if (L == 0) {
            if (bid < 384) {
                const int og = bid % 24, ks = bid / 24;
                dev_gemm<false>(p.tgt, D, Wqkv, D, p.Pqkv + (size_t)ks * B * 3 * D,
                                3 * D, og * 128, ks * 64, 2, sm);
            }
            GB();
            if (bid < 192) dev_finish<16, false, 3 * D>(p.Pqkv, bqkv, p.qkv);
            GB();
#pragma unroll 1
            for (int j = 0; j < 2; ++j) {
                const int pair = bid * 2 + j;
                dev_attn<TT, true>(p.qkv, nullptr, pair >> 4, pair & 15,
                                   p.K0, p.V0, T, p.ctx, sm);
            }
            GB();
            if (bid < 128) {
                const int og = bid & 7, ks = bid >> 3;
                dev_gemm<true>(p.ctx, D, p.sa_oW, D, p.PA + (size_t)ks * B * D, D,
                               og * 128, ks * 64, 2, sm);
            }
            GB();
        } else {
            const float* cache_i = p.cache + (size_t)L * T * B * D;
            if (bid < 128) {
                const int og = bid & 7, ks = bid >> 3;
                dev_gemm<true>(p.x, D, Wqkv, D, p.Pq + (size_t)ks * B * D, D,
                               og * 128, ks * 64, 2, sm);
            }
            GB();
            if (bid < 64) dev_finish<16, false, D>(p.Pq, bqkv, p.q);
            GB();
            if (bid < 128)
                dev_gemm_u(p.q, Wqkv + (size_t)D * D, bid >> 3, (bid & 7) * 128,
                           p.u, sm);
            GB();
            dev_sattn(cache_i, p.x, p.u, bid >> 3, bid & 7, p.wp8, p.sums8, sm);
            GB();
            if (bid < 256)
                dev_gemm_ctx(p.wp8, p.sums8, Wqkv + (size_t)2 * D * D, bid >> 4,
                             bid & 15, p.Pc + (size_t)(bid & 15) * B * D, sm);
            GB();
            if (bid < 64) dev_finish<16, false, D>(p.Pc, bqkv + 2 * D, p.ctx);
            GB();
            if (bid < 128) {
                const int og = bid & 7, ks = bid >> 3;
                dev_gemm<true>(p.ctx, D, p.sa_oW + (size_t)L * D * D, D,
                               p.PA + (size_t)ks * B * D, D, og * 128, ks * 64, 2, sm);
            }
            GB();
        }

        if (bid < B)
            dev_ln<16>(p.PA, p.sa_ob + (size_t)L * D, xin,
                       p.ln1g + (size_t)L * D, p.ln1b + (size_t)L * D, p.x, bid, sm);
        GB();

        // cross attention
        if (bid < 128) {
            const int og = bid & 7, ks = bid >> 3;
            dev_gemm<true>(p.x, D, p.ca_qW + (size_t)L * D * D, D,
                           p.PA + (size_t)ks * B * D, D, og * 128, ks * 64, 2, sm);
        }
        GB();
        {
            const float* Kc = p.K_mem + (size_t)L * B * H * SMEM * DH;
            const float* Vc = p.V_mem + (size_t)L * B * H * SMEM * DH;
#pragma unroll 1
            for (int j = 0; j < 2; ++j) {
                const int pair = bid * 2 + j;
                dev_attn<SMEM, false>(p.PA, p.ca_qb + (size_t)L * D,
                                      pair >> 4, pair & 15, Kc, Vc, SMEM, p.ctx, sm);
            }
        }
        GB();
        if (bid < 128) {
            const int og = bid & 7, ks = bid >> 3;
            dev_gemm<true>(p.ctx, D, p.ca_oW + (size_t)L * D * D, D,
                           p.PA + (size_t)ks * B * D, D, og * 128, ks * 64, 2, sm);
        }
        GB();
        if (bid < B)
            dev_ln<16>(p.PA, p.ca_ob + (size_t)L * D, p.x,
                       p.ln2g + (size_t)L * D, p.ln2b + (size_t)L * D, p.x, bid, sm);
        GB();

        // FFN
        if (bid < 256) {
            const int og = bid & 31, ks = bid >> 5;   // 32 og x 8 ks
            dev_gemm<true>(p.x, D, p.W1 + (size_t)L * DFF * D, D,
                           p.Pf1 + (size_t)ks * B * DFF, DFF, og * 128, ks * 128, 4, sm);
        }
        GB();
        if (bid < 256) dev_finish<8, true, DFF>(p.Pf1, p.b1 + (size_t)L * DFF, p.h1);
        GB();
        if (bid < 256) {
            const int og = bid & 7, ks = bid >> 3;    // 8 og x 32 ks
            dev_gemm<true>(p.h1, DFF, p.W2 + (size_t)L * D * DFF, DFF,
                           p.Pf2 + (size_t)ks * B * D, D, og * 128, ks * 128, 4, sm);
        }
        GB();
        {
            float* lnout = (L == NLAYER - 1) ? p.out : p.x;
            if (bid < B)
                dev_ln<32>(p.Pf2, p.b2 + (size_t)L * D, p.x,
                           p.ln3g + (size_t)L * D, p.ln3b + (size_t)L * D,
                           lnout, bid, sm);
        }
        GB();
    }
#undef GB
}

// ---------------------------------------------------------------------------
extern "C" void kernel_launch(void* const* d_in, const int* in_sizes, int n_in,
                              void* d_out, int out_size, void* d_ws, size_t ws_size,
                              hipStream_t stream)
{
    hipMemsetAsync(d_ws, 0, 16384, stream);   // zero barrier counters

    float* ws = (float*)d_ws;
    MP p;
    p.tgt   = (const float*)d_in[0];
    p.cache = (const float*)d_in[1];
    p.K0    = (const float*)d_in[2];
    p.V0    = (const float*)d_in[3];
    p.K_mem = (const float*)d_in[4];
    p.V_mem = (const float*)d_in[5];
    p.sa_W  = (const float*)d_in[6];
    p.sa_b  = (const float*)d_in[7];
    p.sa_oW = (const float*)d_in[8];
    p.sa_ob = (const float*)d_in[9];
    p.ca_qW = (const float*)d_in[10];
    p.ca_qb = (const float*)d_in[11];
    p.ca_oW = (const float*)d_in[12];
    p.ca_ob = (const float*)d_in[13];
    p.W1    = (const float*)d_in[14];
    p.b1    = (const float*)d_in[15];
    p.W2    = (const float*)d_in[16];
    p.b2    = (const float*)d_in[17];
    p.ln1g  = (const float*)d_in[18];
    p.ln1b  = (const float*)d_in[19];
    p.ln2g  = (const float*)d_in[20];
    p.ln2b  = (const float*)d_in[21];
    p.ln3g  = (const float*)d_in[22];
    p.ln3b  = (const float*)d_in[23];

    p.bar   = (unsigned*)d_ws;               // 4096 u32 = 16 KB
    float* base = ws + 4096;
    p.x     = base;                           // 65,536
    p.ctx   = p.x + 65536;                    // 65,536
    p.q     = p.ctx + 65536;                  // 65,536
    p.qkv   = p.q + 65536;                    // 196,608
    p.u     = p.qkv + 196608;                 // 1,048,576
    p.Pq    = p.u + 1048576;                  // 16*B*D = 1,048,576
    p.PA    = p.Pq + 1048576;                 // 16*B*D = 1,048,576
    p.Pc    = p.PA + 1048576;                 // 16*B*D = 1,048,576
    p.h1    = p.Pc + 1048576;                 // B*DFF = 262,144
    p.Pf2   = p.h1 + 262144;                  // 32*B*D = 2,097,152
    float* R = p.Pf2 + 2097152;               // time-shared: 8,388,608
    p.wp8   = R;                              // 8*B*H*D (self-attn)
    p.Pqkv  = R;                              // 16*B*3D (L0)
    p.Pf1   = R;                              // 8*B*DFF (FFN)
    p.sums8 = R + 8388608;                    // 8,192
    p.out   = (float*)d_out;

    mega<<<dim3(NBLK), dim3(256), 0, stream>>>(p);
}